// Round 4
// baseline (252.791 us; speedup 1.0000x reference)
//
#include <hip/hip_runtime.h>
#include <hip/hip_bf16.h>
#include <stdint.h>

// ---------------------------------------------------------------------------
// MultiHeadAttention fused forward, bf16-MFMA pipeline.
// B=4, T=2048, D=1024, H=16, HD=64.  Input order: x, Wk, Wq, Wv, Wp, bp (fp32).
// R13: gemm_qkv -> faithful m201 8-phase port: 256x256/BK=64, 8 waves 2Mx4N
//      (per-wave 128x64: 24 ds_read_b128 per 64 MFMA -> LDS pipe fits under
//      matrix pipe, unlike R11's 4Mx2N), 4 phases/K-tile each
//      {ds_read issued BEFORE barrier || 2 gl_lds stage -> barrier ->
//       setprio1 16 MFMA setprio0 -> barrier}, counted vmcnt(2) once per
//      K-tile. attn = R12 body (won -8.6us), gemm_proj/cvt = R9 bodies.
// ---------------------------------------------------------------------------

typedef __bf16 bf16x8 __attribute__((ext_vector_type(8)));
typedef float floatx4 __attribute__((ext_vector_type(4)));
typedef unsigned short ushort_t;
typedef unsigned short ushortx8 __attribute__((ext_vector_type(8)));
typedef unsigned short ushortx4 __attribute__((ext_vector_type(4)));
typedef short shortx4 __attribute__((ext_vector_type(4)));

#define MFMA16(a, b, c) __builtin_amdgcn_mfma_f32_16x16x32_bf16((a), (b), (c), 0, 0, 0)
#define MFMA16K16(a, b, c) __builtin_amdgcn_mfma_f32_16x16x16bf16_1k((a), (b), (c), 0, 0, 0)
#define EXP2F(x) __builtin_amdgcn_exp2f(x)

static __device__ __forceinline__ ushort_t f2bfu(float f) {
  union { float f; unsigned u; } v; v.f = f;
  unsigned r = v.u + 0x7FFFu + ((v.u >> 16) & 1u);  // RNE
  return (ushort_t)(r >> 16);
}

// pack two floats' bf16-truncations into one dword: (hi<<16)|lo
static __device__ __forceinline__ unsigned pack_bf2(float lo, float hi) {
  return __builtin_amdgcn_perm(__float_as_uint(hi), __float_as_uint(lo), 0x07060302);
}

// async 16B global -> LDS DMA (dest is wave-uniform base + lane*16)
static __device__ __forceinline__ void gl_lds16(const void* g, void* l) {
  __builtin_amdgcn_global_load_lds(
      (const __attribute__((address_space(1))) void*)g,
      (__attribute__((address_space(3))) void*)l, 16, 0, 0);
}

// ---- fp32 -> bf16 cast, all 5 tensors in one launch (dst regions contiguous)
__global__ void cvt_all(const float* __restrict__ x,  const float* __restrict__ wk,
                        const float* __restrict__ wq, const float* __restrict__ wv,
                        const float* __restrict__ wp, ushortx4* __restrict__ dst) {
  const int i = blockIdx.x * blockDim.x + threadIdx.x;  // float4 units
  const float4* src; int off;
  if (i < 2097152) { src = (const float4*)x; off = i; }
  else {
    const int r = i - 2097152;
    const int sel = r >> 18;                 // 262144 float4 per weight
    off = r & 262143;
    src = (const float4*)(sel == 0 ? wk : sel == 1 ? wq : sel == 2 ? wv : wp);
  }
  const float4 f = src[off];
  ushortx4 o;
  o[0] = f2bfu(f.x); o[1] = f2bfu(f.y); o[2] = f2bfu(f.z); o[3] = f2bfu(f.w);
  dst[i] = o;
}

// ---------------------------------------------------------------------------
// QKV GEMM: C[m,n] = sum_k X[m,k] * W[n,k]   (M=8192, N=1024, K=1024)
// 256x256 tile, BK=64, 8 waves (2Mx4N), per-wave 128x64 output, acc[8][4].
// LDS 128 KiB double-buffer (As[2]/Bs[2]). Grid 384 (1 blk/CU, 1.5 rounds).
// Per K-tile, 4 phases; phase q computes C-quadrant q (rows 2q..2q+1) x K=64:
//   ph0: stage 2 (next tile) -> vmcnt(2) -> barrier -> read B(8)+A0(4) ->
//        setprio1 16 MFMA setprio0 -> barrier
//   ph1..3: read Aq(4) EARLY; stage 2; barrier; setprio1 16 MFMA setprio0;
//        barrier   (read latency absorbed by barrier wait - the m196 lever)
// vmcnt(2) certifies current tile's 8 loads (next tile's first 2 in flight);
// never drains to 0 mid-loop. Accumulation order identical to R9/R10.
// XCD remap: same m-tile -> same linear%8 -> same XCD.
// ---------------------------------------------------------------------------
__global__ __launch_bounds__(512, 2) void gemm_qkv(
    const ushort_t* __restrict__ X,
    const ushort_t* __restrict__ Wq, const ushort_t* __restrict__ Wk,
    const ushort_t* __restrict__ Wv,
    ushort_t* __restrict__ qb, ushort_t* __restrict__ kb, ushort_t* __restrict__ vtb)
{
  // XCD-aware relabel: grid 384 flat, L in [0,384)
  const int L = (int)blockIdx.x;
  const int rr = L & 7, mm = L >> 3;        // mm 0..47
  const int m0 = (rr + 8 * (mm & 3)) * 256; // 32 m-tiles; same m-tile -> same rr
  const int rest = mm >> 2;                 // 0..11
  const int n0 = (rest & 3) * 256;          // 4 n-tiles
  const int z = rest >> 2;                  // 0..2

  const ushort_t* Bm = (z == 0) ? Wq : (z == 1) ? Wk : Wv;

  __shared__ ushort_t Asm[2][256 * 64];
  __shared__ ushort_t Bsm[2][256 * 64];

  const int tid = threadIdx.x;
  const int w = tid >> 6, lane = tid & 63, g = lane >> 4, c = lane & 15;
  const int wm = w >> 2, wn = w & 3;        // 2M x 4N wave grid
  const int cswz = c & 7;

  floatx4 acc[8][4];
  const floatx4 zero4 = {0.f, 0.f, 0.f, 0.f};
#pragma unroll
  for (int i = 0; i < 8; ++i)
#pragma unroll
    for (int j = 0; j < 4; ++j) acc[i][j] = zero4;

  const int srow = tid >> 3;                       // 0..63 (64 rows per pass)
  const int gsw  = ((tid & 7) ^ (srow & 7)) * 8;   // pre-swizzled source chunk

  // prologue: stage kt=0 (A passes 0..3, B passes 0..3) into buffer 0
#pragma unroll
  for (int p = 0; p < 4; ++p) {
    gl_lds16(&X [(size_t)(m0 + p * 64 + srow) * 1024 + gsw], &Asm[0][p * 4096 + tid * 8]);
    gl_lds16(&Bm[(size_t)(n0 + p * 64 + srow) * 1024 + gsw], &Bsm[0][p * 4096 + tid * 8]);
  }

#pragma unroll 1
  for (int kt = 0; kt < 16; ++kt) {
    const int cur = kt & 1, nb = cur ^ 1;
    const ushort_t* Ac = Asm[cur];
    const ushort_t* Bc = Bsm[cur];
    const int kn = (kt + 1) * 64;
    const bool stagenext = (kt < 15);

    // ---- phase 0: stage pass 0, certify current tile, quadrant 0
    if (stagenext) {
      gl_lds16(&X [(size_t)(m0 + srow) * 1024 + kn + gsw], &Asm[nb][tid * 8]);
      gl_lds16(&Bm[(size_t)(n0 + srow) * 1024 + kn + gsw], &Bsm[nb][tid * 8]);
      asm volatile("s_waitcnt vmcnt(2)" ::: "memory");
    } else {
      asm volatile("s_waitcnt vmcnt(0)" ::: "memory");
    }
    __builtin_amdgcn_s_barrier();

    // all 8 B-frags (held across the 4 phases) + quadrant-0 A-frags
    bf16x8 bfr[4][2];
#pragma unroll
    for (int j = 0; j < 4; ++j)
#pragma unroll
      for (int kk = 0; kk < 2; ++kk)
        bfr[j][kk] = *reinterpret_cast<const bf16x8*>(
            &Bc[(wn * 64 + j * 16 + c) * 64 + ((kk * 4 + g) ^ cswz) * 8]);

    {
      bf16x8 af[2][2];
#pragma unroll
      for (int ii = 0; ii < 2; ++ii)
#pragma unroll
        for (int kk = 0; kk < 2; ++kk)
          af[ii][kk] = *reinterpret_cast<const bf16x8*>(
              &Ac[(wm * 128 + ii * 16 + c) * 64 + ((kk * 4 + g) ^ cswz) * 8]);
      __builtin_amdgcn_s_setprio(1);
#pragma unroll
      for (int ii = 0; ii < 2; ++ii)
#pragma unroll
        for (int j = 0; j < 4; ++j)
#pragma unroll
          for (int kk = 0; kk < 2; ++kk)
            acc[ii][j] = MFMA16(af[ii][kk], bfr[j][kk], acc[ii][j]);
      __builtin_amdgcn_s_setprio(0);
    }
    __builtin_amdgcn_s_barrier();

    // ---- phases 1..3: read A-quadrant EARLY, stage pass q, barrier, MFMA
#pragma unroll
    for (int q = 1; q < 4; ++q) {
      bf16x8 af[2][2];
#pragma unroll
      for (int ii = 0; ii < 2; ++ii)
#pragma unroll
        for (int kk = 0; kk < 2; ++kk)
          af[ii][kk] = *reinterpret_cast<const bf16x8*>(
              &Ac[(wm * 128 + (q * 2 + ii) * 16 + c) * 64 + ((kk * 4 + g) ^ cswz) * 8]);
      if (stagenext) {
        gl_lds16(&X [(size_t)(m0 + q * 64 + srow) * 1024 + kn + gsw],
                 &Asm[nb][q * 4096 + tid * 8]);
        gl_lds16(&Bm[(size_t)(n0 + q * 64 + srow) * 1024 + kn + gsw],
                 &Bsm[nb][q * 4096 + tid * 8]);
      }
      __builtin_amdgcn_s_barrier();
      __builtin_amdgcn_s_setprio(1);
#pragma unroll
      for (int ii = 0; ii < 2; ++ii)
#pragma unroll
        for (int j = 0; j < 4; ++j)
#pragma unroll
          for (int kk = 0; kk < 2; ++kk)
            acc[q * 2 + ii][j] = MFMA16(af[ii][kk], bfr[j][kk], acc[q * 2 + ii][j]);
      __builtin_amdgcn_s_setprio(0);
      __builtin_amdgcn_s_barrier();
    }
  }

  // Epilogue: C/D layout row = g*4+r, col = c within each 16x16 tile.
#pragma unroll
  for (int i = 0; i < 8; ++i) {
#pragma unroll
    for (int j = 0; j < 4; ++j) {
      const int mbase = m0 + wm * 128 + i * 16 + g * 4;
      const int n = n0 + wn * 64 + j * 16 + c;
      const int h = n >> 6, d = n & 63;
      if (z == 2) {
        // V^T: [(bb*16+h)*64+d]*2048 + t, 4 consecutive t -> 8B store
        const int bb = mbase >> 11, t = mbase & 2047;
        ushortx4 pk;
#pragma unroll
        for (int r = 0; r < 4; ++r) pk[r] = f2bfu(acc[i][j][r]);
        *reinterpret_cast<ushortx4*>(&vtb[(size_t)((bb * 16 + h) * 64 + d) * 2048 + t]) = pk;
      } else {
        ushort_t* ob = (z == 0) ? qb : kb;
#pragma unroll
        for (int r = 0; r < 4; ++r) {
          const int m = mbase + r;
          const int bb = m >> 11, t = m & 2047;
          ob[(size_t)((bb * 16 + h) * 2048 + t) * 64 + d] = f2bfu(acc[i][j][r]);
        }
      }
    }
  }
}

// ---------------------------------------------------------------------------
// Flash attention (causal), register-resident P^T (R12 body - proven win).
// 64-key tiles, double-buffered K/V staging, prefetch-before-compute,
// counted s_waitcnt vmcnt(4) + raw barrier per tile.
// ---------------------------------------------------------------------------
__global__ __launch_bounds__(256, 4) void attn_kernel(
    const ushort_t* __restrict__ qbuf, const ushort_t* __restrict__ kbuf,
    const ushort_t* __restrict__ vtbuf, ushort_t* __restrict__ obuf)
{
  // XCD-aware relabel: grid (16,16,4) flat L in [0,1024)
  const int L = (int)(blockIdx.x + 16 * (blockIdx.y + 16 * blockIdx.z));
  const int rr = L & 7, mm = L >> 3;        // mm 0..127
  const int j = mm >> 3;                    // q-tile pair index 0..15
  const int bhl = rr * 8 + (mm & 7);        // 0..63, same bh -> same rr
  const int h = bhl & 15, b = bhl >> 4;

  const int tid = threadIdx.x, w = tid >> 6, lane = tid & 63, g = lane >> 4, c = lane & 15;

  __shared__ ushort_t Kl[2][64 * 64];     // [buf][key][d], XOR-swizzled 8-chunk rows
  __shared__ ushort_t Vl[2][64 * 64];     // [buf][d][key], XOR-swizzled 8-chunk rows

  const size_t bh = (size_t)(b * 16 + h);
  const ushort_t* kb_bh = kbuf + bh * 2048 * 64;
  const ushort_t* vt_bh = vtbuf + bh * 64 * 2048;
  const ushort_t* qb_bh = qbuf + bh * 2048 * 64;

  const int rb0 = j * 64 + w * 16;           // grp 0 q-rows (diag tile j)
  const int rb1 = (31 - j) * 64 + w * 16;    // grp 1 q-rows (diag tile 31-j)

  // Q B-frags (x32): B[n=q=lane&15][k=d=quad*8+j]: contiguous 16B loads
  bf16x8 aq0[2], aq1[2];
  {
    const ushort_t* qp0 = qb_bh + (size_t)(rb0 + c) * 64;
    aq0[0] = *reinterpret_cast<const bf16x8*>(qp0 + g * 8);
    aq0[1] = *reinterpret_cast<const bf16x8*>(qp0 + 32 + g * 8);
    const ushort_t* qp1 = qb_bh + (size_t)(rb1 + c) * 64;
    aq1[0] = *reinterpret_cast<const bf16x8*>(qp1 + g * 8);
    aq1[1] = *reinterpret_cast<const bf16x8*>(qp1 + 32 + g * 8);
  }

  // O^T accumulators: [grp][td] tile, lane holds d = td*16+g*4+r, q = rb+c
  floatx4 oacc0[4], oacc1[4];
  float l0 = 0.f, l1 = 0.f;
  const floatx4 zero4 = {0.f, 0.f, 0.f, 0.f};
#pragma unroll
  for (int td = 0; td < 4; ++td) { oacc0[td] = zero4; oacc1[td] = zero4; }

  // staging helpers: 2 passes x 32 rows x (8 lanes * 16B) per 64x64 tile
  const int srow8 = tid >> 3;                        // 0..31
  const int gswz  = ((tid & 7) ^ (srow8 & 7)) * 8;   // swizzled source chunk (shorts)

  const float SCALE = 0.18033688011112042f;  // 0.125 * log2(e)

  const int NT = 32 - j;   // 64-key subtiles needed (grp1 lim = 31-j)

  auto stage = [&](int ti, int buf) {        // 4 gl_lds per thread
    const int key0 = ti * 64;
#pragma unroll
    for (int p = 0; p < 2; ++p) {
      gl_lds16(&kb_bh[(size_t)(key0 + p * 32 + srow8) * 64 + gswz],
               &Kl[buf][p * 2048 + tid * 8]);
      gl_lds16(&vt_bh[(size_t)(p * 32 + srow8) * 2048 + key0 + gswz],
               &Vl[buf][p * 2048 + tid * 8]);
    }
  };

  stage(0, 0);

  for (int ti = 0; ti < NT; ++ti) {
    const int cur = ti & 1;
    if (ti + 1 < NT) {
      stage(ti + 1, cur ^ 1);                         // prefetch next tile
      asm volatile("s_waitcnt vmcnt(4)" ::: "memory"); // this tile's 4 landed
    } else {
      asm volatile("s_waitcnt vmcnt(0)" ::: "memory");
    }
    __builtin_amdgcn_s_barrier();

    const ushort_t* Kc = Kl[cur];
    const ushort_t* Vc = Vl[cur];
    const int key0s = ti * 64;

#pragma unroll
    for (int grp = 0; grp < 2; ++grp) {
      const int lim = (grp == 0) ? j : 31 - j;
      if (ti > lim) continue;        // uniform scalar branch
      const int rb = (grp == 0) ? rb0 : rb1;
      const bf16x8 b0 = (grp == 0) ? aq0[0] : aq1[0];
      const bf16x8 b1 = (grp == 0) ? aq0[1] : aq1[1];

      float pv[4][4];
#pragma unroll
      for (int t4 = 0; t4 < 4; ++t4) {
        // S^T tile: A = K-frag (m=key=lane&15 -> row key0s+t4*16+c)
        const int krow = t4 * 16 + c;
        const bf16x8 k0f = *reinterpret_cast<const bf16x8*>(&Kc[krow * 64 + ((g) ^ (c & 7)) * 8]);
        const bf16x8 k1f = *reinterpret_cast<const bf16x8*>(&Kc[krow * 64 + ((4 + g) ^ (c & 7)) * 8]);
        floatx4 sa = zero4;
        sa = MFMA16(k0f, b0, sa);
        sa = MFMA16(k1f, b1, sa);
        // C/D: lane c = q-col, reg r -> key = key0s + t4*16 + g*4 + r
        if (ti == lim) {             // diagonal tile: causal mask
          const int q = rb + c;
#pragma unroll
          for (int r = 0; r < 4; ++r) {
            const int key = key0s + t4 * 16 + g * 4 + r;
            const float e = EXP2F(sa[r] * SCALE);
            pv[t4][r] = (key <= q) ? e : 0.f;
          }
        } else {
#pragma unroll
          for (int r = 0; r < 4; ++r) pv[t4][r] = EXP2F(sa[r] * SCALE);
        }
      }
      // l partial (each lane's 16 values all belong to q = rb+c)
      float lsum = 0.f;
#pragma unroll
      for (int t4 = 0; t4 < 4; ++t4)
        lsum += (pv[t4][0] + pv[t4][1]) + (pv[t4][2] + pv[t4][3]);
      if (grp == 0) l0 += lsum; else l1 += lsum;

      // PV: O^T += V^T * P^T via mfma 16x16x16 (P^T regs ARE the B-frag)
#pragma unroll
      for (int t4 = 0; t4 < 4; ++t4) {
        union { unsigned u[2]; shortx4 v; } pk;
        pk.u[0] = pack_bf2(pv[t4][0], pv[t4][1]);
        pk.u[1] = pack_bf2(pv[t4][2], pv[t4][3]);
        const int cc = t4 * 2 + (g >> 1);              // V key-chunk index (0..7)
        const int ko = (g & 1) * 4;                    // within-chunk key
#pragma unroll
        for (int td = 0; td < 4; ++td) {
          const shortx4 va = *reinterpret_cast<const shortx4*>(
              &Vc[(td * 16 + c) * 64 + (cc ^ (c & 7)) * 8 + ko]);
          if (grp == 0) oacc0[td] = MFMA16K16(va, pk.v, oacc0[td]);
          else          oacc1[td] = MFMA16K16(va, pk.v, oacc1[td]);
        }
      }
    }
    __builtin_amdgcn_s_barrier();   // all waves done reading buf[cur] before
                                    // next iter's stage overwrites it
  }

  // l: reduce across quads (q = c; partial per quad g) then normalize+store
#pragma unroll
  for (int grp = 0; grp < 2; ++grp) {
    float ls = (grp == 0) ? l0 : l1;
    ls += __shfl_xor(ls, 16, 64);
    ls += __shfl_xor(ls, 32, 64);
    const float inv = 1.f / ls;
    const int q = ((grp == 0) ? rb0 : rb1) + c;
    ushort_t* ob = &obuf[((size_t)(b * 2048 + q) * 16 + h) * 64];
#pragma unroll
    for (int td = 0; td < 4; ++td) {
      const floatx4 oa = (grp == 0) ? oacc0[td] : oacc1[td];
      ushortx4 pk;
#pragma unroll
      for (int r = 0; r < 4; ++r) pk[r] = f2bfu(oa[r] * inv);
      *reinterpret_cast<ushortx4*>(&ob[td * 16 + g * 4]) = pk;
    }
  }
}

// ---------------------------------------------------------------------------
// Output projection: out[m,n] = sum_k O[m,k] * Wp[n,k] + bp[n], fp32 out.
// R9 body. XCD remap as in gemm_qkv.
// ---------------------------------------------------------------------------
__global__ __launch_bounds__(256) void gemm_proj(
    const ushort_t* __restrict__ A, const ushort_t* __restrict__ Wp,
    const float* __restrict__ bias, float* __restrict__ out)
{
  const int L = (int)(blockIdx.x + 64 * blockIdx.y);  // grid (64,8), L in [0,512)
  const int rr = L & 7, mm = L >> 3;                  // mm 0..63
  const int m0 = (rr + 8 * (mm & 7)) * 128;
  const int n0 = (mm >> 3) * 128;

  __shared__ ushort_t Al[128 * 64];
  __shared__ ushort_t Bl[128 * 64];
  const int tid = threadIdx.x;
  const int w = tid >> 6, lane = tid & 63, g = lane >> 4, c = lane & 15;
  const int wm = w >> 1, wn = w & 1;
  const int cswz = c & 7;

  floatx4 acc[4][4];
  const floatx4 zero4 = {0.f, 0.f, 0.f, 0.f};
#pragma unroll
  for (int i = 0; i < 4; ++i)
#pragma unroll
    for (int j = 0; j < 4; ++j) acc[i][j] = zero4;

  const int srow = tid >> 3;
  const int gsw  = ((tid & 7) ^ (srow & 7)) * 8;

  for (int k0 = 0; k0 < 1024; k0 += 64) {
#pragma unroll
    for (int p = 0; p < 4; ++p) {
      const int row = p * 32 + srow;
      gl_lds16(&A [(size_t)(m0 + row) * 1024 + k0 + gsw], &Al[p * 2048 + tid * 8]);
      gl_lds16(&Wp[(size_t)(n0 + row) * 1024 + k0 + gsw], &Bl[p * 2048 + tid * 8]);
    }
    __syncthreads();
#pragma unroll
    for (int kk = 0; kk < 2; ++kk) {
      bf16x8 af[4], bfr[4];
#pragma unroll
      for (int i = 0; i < 4; ++i) {
        const int sw = ((kk * 4 + g) ^ cswz) * 8;
        af[i]  = *reinterpret_cast<const bf16x8*>(&Al[(wm * 64 + i * 16 + c) * 64 + sw]);
        bfr[i] = *reinterpret_cast<const bf16x8*>(&Bl[(wn * 64 + i * 16 + c) * 64 + sw]);
      }
#pragma unroll
      for (int i = 0; i < 4; ++i)
#pragma unroll
        for (int j = 0; j < 4; ++j)
          acc[i][j] = MFMA16(af[i], bfr[j], acc[i][j]);
    }
    __syncthreads();
  }

#pragma unroll
  for (int i = 0; i < 4; ++i) {
#pragma unroll
    for (int j = 0; j < 4; ++j) {
      const int n = n0 + wn * 64 + j * 16 + c;
      const float bv = bias[n];
#pragma unroll
      for (int r = 0; r < 4; ++r) {
        const int m = m0 + wm * 64 + i * 16 + g * 4 + r;
        out[(size_t)m * 1024 + n] = acc[i][j][r] + bv;
      }
    }
  }
}

extern "C" void kernel_launch(void* const* d_in, const int* in_sizes, int n_in,
                              void* d_out, int out_size, void* d_ws, size_t ws_size,
                              hipStream_t stream) {
  const float* x  = (const float*)d_in[0];
  const float* Wk = (const float*)d_in[1];   // input order: x, Wk, Wq, Wv, Wp, bp
  const float* Wq = (const float*)d_in[2];
  const float* Wv = (const float*)d_in[3];
  const float* Wp = (const float*)d_in[4];
  const float* bp = (const float*)d_in[5];
  float* out = (float*)d_out;

  char* ws = (char*)d_ws;
  const size_t SZ_X = (size_t)8192 * 1024 * 2;  // 16 MB bf16
  const size_t SZ_W = (size_t)1024 * 1024 * 2;  //  2 MB bf16
  ushort_t* xb    = (ushort_t*)ws;  ws += SZ_X;  // xb..wpb contiguous (cvt_all dst)
  ushort_t* wkb   = (ushort_t*)ws;  ws += SZ_W;
  ushort_t* wqb   = (ushort_t*)ws;  ws += SZ_W;
  ushort_t* wvb   = (ushort_t*)ws;  ws += SZ_W;
  ushort_t* wpb   = (ushort_t*)ws;  ws += SZ_W;
  ushort_t* qbuf  = (ushort_t*)ws;  ws += SZ_X;
  ushort_t* kbuf  = (ushort_t*)ws;  ws += SZ_X;
  ushort_t* vtbuf = (ushort_t*)ws;  ws += SZ_X;
  ushort_t* obuf  = xb;  // x is consumed by gemm_qkv before attn writes obuf

  cvt_all<<<12288, 256, 0, stream>>>(x, Wk, Wq, Wv, Wp, (ushortx4*)xb);

  gemm_qkv<<<dim3(384), 512, 0, stream>>>(xb, wqb, wkb, wvb, qbuf, kbuf, vtbuf);
  attn_kernel<<<dim3(16, 16, 4), 256, 0, stream>>>(qbuf, kbuf, vtbuf, obuf);
  gemm_proj<<<dim3(64, 8), 256, 0, stream>>>(obuf, wpb, bp, out);
}

// Round 5
// 250.865 us; speedup vs baseline: 1.0077x; 1.0077x over previous
//
#include <hip/hip_runtime.h>
#include <hip/hip_bf16.h>
#include <stdint.h>

// ---------------------------------------------------------------------------
// MultiHeadAttention fused forward, bf16-MFMA pipeline.
// B=4, T=2048, D=1024, H=16, HD=64.  Input order: x, Wk, Wq, Wv, Wp, bp (fp32).
// R14: gemm_qkv PERMANENTLY reverted to R9 body (three 256-tile pipeline ports
//      all regressed: R10 72.9, R11 73.7, R13 82.1 vs R9 63.5-65.7us).
//      attn: K/V A-fragment LDS reads deduplicated across the two q-tile
//      groups (they never depended on grp) — dual-group subtiles (ti<=j) now
//      load each K/V frag ONCE and feed both groups' MFMAs (~26% of attn LDS
//      reads removed). Accumulator op order unchanged -> identical numerics.
//      attn staging = R12 (counted vmcnt(4) double-buffer, proven -8.6us).
// ---------------------------------------------------------------------------

typedef __bf16 bf16x8 __attribute__((ext_vector_type(8)));
typedef float floatx4 __attribute__((ext_vector_type(4)));
typedef unsigned short ushort_t;
typedef unsigned short ushortx8 __attribute__((ext_vector_type(8)));
typedef unsigned short ushortx4 __attribute__((ext_vector_type(4)));
typedef short shortx4 __attribute__((ext_vector_type(4)));

#define MFMA16(a, b, c) __builtin_amdgcn_mfma_f32_16x16x32_bf16((a), (b), (c), 0, 0, 0)
#define MFMA16K16(a, b, c) __builtin_amdgcn_mfma_f32_16x16x16bf16_1k((a), (b), (c), 0, 0, 0)
#define EXP2F(x) __builtin_amdgcn_exp2f(x)

static __device__ __forceinline__ ushort_t f2bfu(float f) {
  union { float f; unsigned u; } v; v.f = f;
  unsigned r = v.u + 0x7FFFu + ((v.u >> 16) & 1u);  // RNE
  return (ushort_t)(r >> 16);
}

// pack two floats' bf16-truncations into one dword: (hi<<16)|lo
static __device__ __forceinline__ unsigned pack_bf2(float lo, float hi) {
  return __builtin_amdgcn_perm(__float_as_uint(hi), __float_as_uint(lo), 0x07060302);
}

// async 16B global -> LDS DMA (dest is wave-uniform base + lane*16)
static __device__ __forceinline__ void gl_lds16(const void* g, void* l) {
  __builtin_amdgcn_global_load_lds(
      (const __attribute__((address_space(1))) void*)g,
      (__attribute__((address_space(3))) void*)l, 16, 0, 0);
}

// ---- fp32 -> bf16 cast, all 5 tensors in one launch (dst regions contiguous)
__global__ void cvt_all(const float* __restrict__ x,  const float* __restrict__ wk,
                        const float* __restrict__ wq, const float* __restrict__ wv,
                        const float* __restrict__ wp, ushortx4* __restrict__ dst) {
  const int i = blockIdx.x * blockDim.x + threadIdx.x;  // float4 units
  const float4* src; int off;
  if (i < 2097152) { src = (const float4*)x; off = i; }
  else {
    const int r = i - 2097152;
    const int sel = r >> 18;                 // 262144 float4 per weight
    off = r & 262143;
    src = (const float4*)(sel == 0 ? wk : sel == 1 ? wq : sel == 2 ? wv : wp);
  }
  const float4 f = src[off];
  ushortx4 o;
  o[0] = f2bfu(f.x); o[1] = f2bfu(f.y); o[2] = f2bfu(f.z); o[3] = f2bfu(f.w);
  dst[i] = o;
}

// ---------------------------------------------------------------------------
// QKV GEMM: C[m,n] = sum_k X[m,k] * W[n,k]   (M=8192, N=1024, K=1024)
// R9 body: 128x128 tile, m97 structure + XOR bank swizzle. z=0->Q, z=1->K,
// z=2->V^T. XCD remap: same m0 -> same linear%8 -> same XCD L2.
// ---------------------------------------------------------------------------
__global__ __launch_bounds__(256) void gemm_qkv(
    const ushort_t* __restrict__ X,
    const ushort_t* __restrict__ Wq, const ushort_t* __restrict__ Wk,
    const ushort_t* __restrict__ Wv,
    ushort_t* __restrict__ qb, ushort_t* __restrict__ kb, ushort_t* __restrict__ vtb)
{
  // XCD-aware relabel of (m0, n0, z): grid (64,8,3) flat L in [0,1536)
  const int L = (int)(blockIdx.x + 64 * (blockIdx.y + 8 * blockIdx.z));
  const int rr = L & 7, mm = L >> 3;           // mm 0..191
  const int m0 = (rr + 8 * (mm & 7)) * 128;    // 64 m-tiles, same tile -> same rr
  const int rest = mm >> 3;                    // 0..23
  const int n0 = (rest & 7) * 128;
  const int z = rest >> 3;

  const ushort_t* Bm = (z == 0) ? Wq : (z == 1) ? Wk : Wv;
  __shared__ ushort_t Al[128 * 64];
  __shared__ ushort_t Bl[128 * 64];
  const int tid = threadIdx.x;
  const int w = tid >> 6, lane = tid & 63, g = lane >> 4, c = lane & 15;
  const int wm = w >> 1, wn = w & 1;
  const int cswz = c & 7;

  floatx4 acc[4][4];
  const floatx4 zero4 = {0.f, 0.f, 0.f, 0.f};
#pragma unroll
  for (int i = 0; i < 4; ++i)
#pragma unroll
    for (int j = 0; j < 4; ++j) acc[i][j] = zero4;

  const int srow = tid >> 3;
  const int gsw  = ((tid & 7) ^ (srow & 7)) * 8;  // swizzled source chunk (shorts)

  for (int k0 = 0; k0 < 1024; k0 += 64) {
#pragma unroll
    for (int p = 0; p < 4; ++p) {
      const int row = p * 32 + srow;
      gl_lds16(&X [(size_t)(m0 + row) * 1024 + k0 + gsw], &Al[p * 2048 + tid * 8]);
      gl_lds16(&Bm[(size_t)(n0 + row) * 1024 + k0 + gsw], &Bl[p * 2048 + tid * 8]);
    }
    __syncthreads();
#pragma unroll
    for (int kk = 0; kk < 2; ++kk) {
      bf16x8 af[4], bfr[4];
#pragma unroll
      for (int i = 0; i < 4; ++i) {
        const int sw = ((kk * 4 + g) ^ cswz) * 8;
        af[i]  = *reinterpret_cast<const bf16x8*>(&Al[(wm * 64 + i * 16 + c) * 64 + sw]);
        bfr[i] = *reinterpret_cast<const bf16x8*>(&Bl[(wn * 64 + i * 16 + c) * 64 + sw]);
      }
#pragma unroll
      for (int i = 0; i < 4; ++i)
#pragma unroll
        for (int j = 0; j < 4; ++j)
          acc[i][j] = MFMA16(af[i], bfr[j], acc[i][j]);
    }
    __syncthreads();
  }

  // Epilogue: C/D layout row = g*4+r, col = c within each 16x16 tile.
#pragma unroll
  for (int i = 0; i < 4; ++i) {
#pragma unroll
    for (int j = 0; j < 4; ++j) {
      const int mbase = m0 + wm * 64 + i * 16 + g * 4;
      const int n = n0 + wn * 64 + j * 16 + c;
      const int h = n >> 6, d = n & 63;
      if (z == 2) {
        // V^T: [(bb*16+h)*64+d]*2048 + t, 4 consecutive t -> 8B store
        const int bb = mbase >> 11, t = mbase & 2047;
        ushortx4 pk;
#pragma unroll
        for (int r = 0; r < 4; ++r) pk[r] = f2bfu(acc[i][j][r]);
        *reinterpret_cast<ushortx4*>(&vtb[(size_t)((bb * 16 + h) * 64 + d) * 2048 + t]) = pk;
      } else {
        ushort_t* ob = (z == 0) ? qb : kb;
#pragma unroll
        for (int r = 0; r < 4; ++r) {
          const int m = mbase + r;
          const int bb = m >> 11, t = m & 2047;
          ob[(size_t)((bb * 16 + h) * 2048 + t) * 64 + d] = f2bfu(acc[i][j][r]);
        }
      }
    }
  }
}

// ---------------------------------------------------------------------------
// Flash attention (causal), register-resident P^T.
// R12 staging (64-key tiles, double-buffered, prefetch-before-compute,
// counted s_waitcnt vmcnt(4)) + R14 dedup: on dual-group subtiles (ti<=j)
// K-frags and V-frags are loaded ONCE and feed both groups' MFMAs (the
// A-operand addresses never depended on grp). Single-group subtiles are the
// unchanged grp1 path. Per-accumulator op order identical to R12.
// ---------------------------------------------------------------------------
__global__ __launch_bounds__(256, 4) void attn_kernel(
    const ushort_t* __restrict__ qbuf, const ushort_t* __restrict__ kbuf,
    const ushort_t* __restrict__ vtbuf, ushort_t* __restrict__ obuf)
{
  // XCD-aware relabel: grid (16,16,4) flat L in [0,1024)
  const int L = (int)(blockIdx.x + 16 * (blockIdx.y + 16 * blockIdx.z));
  const int rr = L & 7, mm = L >> 3;        // mm 0..127
  const int j = mm >> 3;                    // q-tile pair index 0..15
  const int bhl = rr * 8 + (mm & 7);        // 0..63, same bh -> same rr
  const int h = bhl & 15, b = bhl >> 4;

  const int tid = threadIdx.x, w = tid >> 6, lane = tid & 63, g = lane >> 4, c = lane & 15;

  __shared__ ushort_t Kl[2][64 * 64];     // [buf][key][d], XOR-swizzled 8-chunk rows
  __shared__ ushort_t Vl[2][64 * 64];     // [buf][d][key], XOR-swizzled 8-chunk rows

  const size_t bh = (size_t)(b * 16 + h);
  const ushort_t* kb_bh = kbuf + bh * 2048 * 64;
  const ushort_t* vt_bh = vtbuf + bh * 64 * 2048;
  const ushort_t* qb_bh = qbuf + bh * 2048 * 64;

  const int rb0 = j * 64 + w * 16;           // grp 0 q-rows (diag tile j)
  const int rb1 = (31 - j) * 64 + w * 16;    // grp 1 q-rows (diag tile 31-j)

  // Q B-frags (x32): B[n=q=lane&15][k=d=quad*8+j]: contiguous 16B loads
  bf16x8 aq0[2], aq1[2];
  {
    const ushort_t* qp0 = qb_bh + (size_t)(rb0 + c) * 64;
    aq0[0] = *reinterpret_cast<const bf16x8*>(qp0 + g * 8);
    aq0[1] = *reinterpret_cast<const bf16x8*>(qp0 + 32 + g * 8);
    const ushort_t* qp1 = qb_bh + (size_t)(rb1 + c) * 64;
    aq1[0] = *reinterpret_cast<const bf16x8*>(qp1 + g * 8);
    aq1[1] = *reinterpret_cast<const bf16x8*>(qp1 + 32 + g * 8);
  }

  // O^T accumulators: [grp][td] tile, lane holds d = td*16+g*4+r, q = rb+c
  floatx4 oacc0[4], oacc1[4];
  float l0 = 0.f, l1 = 0.f;
  const floatx4 zero4 = {0.f, 0.f, 0.f, 0.f};
#pragma unroll
  for (int td = 0; td < 4; ++td) { oacc0[td] = zero4; oacc1[td] = zero4; }

  // staging helpers: 2 passes x 32 rows x (8 lanes * 16B) per 64x64 tile
  const int srow8 = tid >> 3;                        // 0..31
  const int gswz  = ((tid & 7) ^ (srow8 & 7)) * 8;   // swizzled source chunk (shorts)

  const float SCALE = 0.18033688011112042f;  // 0.125 * log2(e)

  const int NT = 32 - j;   // 64-key subtiles needed (grp1 lim = 31-j)

  auto stage = [&](int ti, int buf) {        // 4 gl_lds per thread
    const int key0 = ti * 64;
#pragma unroll
    for (int p = 0; p < 2; ++p) {
      gl_lds16(&kb_bh[(size_t)(key0 + p * 32 + srow8) * 64 + gswz],
               &Kl[buf][p * 2048 + tid * 8]);
      gl_lds16(&vt_bh[(size_t)(p * 32 + srow8) * 2048 + key0 + gswz],
               &Vl[buf][p * 2048 + tid * 8]);
    }
  };

  stage(0, 0);

  for (int ti = 0; ti < NT; ++ti) {
    const int cur = ti & 1;
    if (ti + 1 < NT) {
      stage(ti + 1, cur ^ 1);                         // prefetch next tile
      asm volatile("s_waitcnt vmcnt(4)" ::: "memory"); // this tile's 4 landed
    } else {
      asm volatile("s_waitcnt vmcnt(0)" ::: "memory");
    }
    __builtin_amdgcn_s_barrier();

    const ushort_t* Kc = Kl[cur];
    const ushort_t* Vc = Vl[cur];
    const int key0s = ti * 64;

    if (ti <= j) {
      // ---- DUAL: both groups active (ti <= j < 16 <= 31-j, so grp1 is
      // never diagonal here). K/V frags loaded once, used by both groups.
      unsigned pk0[4][2], pk1[4][2];
      float lsum0 = 0.f, lsum1 = 0.f;
#pragma unroll
      for (int t4 = 0; t4 < 4; ++t4) {
        const int krow = t4 * 16 + c;
        const bf16x8 k0f = *reinterpret_cast<const bf16x8*>(&Kc[krow * 64 + ((g) ^ (c & 7)) * 8]);
        const bf16x8 k1f = *reinterpret_cast<const bf16x8*>(&Kc[krow * 64 + ((4 + g) ^ (c & 7)) * 8]);
        floatx4 sa0 = zero4, sa1 = zero4;
        sa0 = MFMA16(k0f, aq0[0], sa0);
        sa0 = MFMA16(k1f, aq0[1], sa0);
        sa1 = MFMA16(k0f, aq1[0], sa1);
        sa1 = MFMA16(k1f, aq1[1], sa1);
        float p0[4], p1[4];
        if (ti == j) {               // grp0 diagonal tile: causal mask
          const int q0 = rb0 + c;
#pragma unroll
          for (int r = 0; r < 4; ++r) {
            const int key = key0s + t4 * 16 + g * 4 + r;
            const float e = EXP2F(sa0[r] * SCALE);
            p0[r] = (key <= q0) ? e : 0.f;
          }
        } else {
#pragma unroll
          for (int r = 0; r < 4; ++r) p0[r] = EXP2F(sa0[r] * SCALE);
        }
#pragma unroll
        for (int r = 0; r < 4; ++r) p1[r] = EXP2F(sa1[r] * SCALE);
        lsum0 += (p0[0] + p0[1]) + (p0[2] + p0[3]);
        lsum1 += (p1[0] + p1[1]) + (p1[2] + p1[3]);
        pk0[t4][0] = pack_bf2(p0[0], p0[1]); pk0[t4][1] = pack_bf2(p0[2], p0[3]);
        pk1[t4][0] = pack_bf2(p1[0], p1[1]); pk1[t4][1] = pack_bf2(p1[2], p1[3]);
      }
      l0 += lsum0; l1 += lsum1;

      // PV: shared V-frags, both accumulators
#pragma unroll
      for (int t4 = 0; t4 < 4; ++t4) {
        union { unsigned u[2]; shortx4 v; } w0, w1;
        w0.u[0] = pk0[t4][0]; w0.u[1] = pk0[t4][1];
        w1.u[0] = pk1[t4][0]; w1.u[1] = pk1[t4][1];
        const int cc = t4 * 2 + (g >> 1);              // V key-chunk index (0..7)
        const int ko = (g & 1) * 4;                    // within-chunk key
#pragma unroll
        for (int td = 0; td < 4; ++td) {
          const shortx4 va = *reinterpret_cast<const shortx4*>(
              &Vc[(td * 16 + c) * 64 + (cc ^ (c & 7)) * 8 + ko]);
          oacc0[td] = MFMA16K16(va, w0.v, oacc0[td]);
          oacc1[td] = MFMA16K16(va, w1.v, oacc1[td]);
        }
      }
    } else {
      // ---- SINGLE: grp1 only (unchanged R12 path, lim = 31-j)
      float pv[4][4];
#pragma unroll
      for (int t4 = 0; t4 < 4; ++t4) {
        const int krow = t4 * 16 + c;
        const bf16x8 k0f = *reinterpret_cast<const bf16x8*>(&Kc[krow * 64 + ((g) ^ (c & 7)) * 8]);
        const bf16x8 k1f = *reinterpret_cast<const bf16x8*>(&Kc[krow * 64 + ((4 + g) ^ (c & 7)) * 8]);
        floatx4 sa = zero4;
        sa = MFMA16(k0f, aq1[0], sa);
        sa = MFMA16(k1f, aq1[1], sa);
        if (ti == 31 - j) {          // grp1 diagonal tile: causal mask
          const int q = rb1 + c;
#pragma unroll
          for (int r = 0; r < 4; ++r) {
            const int key = key0s + t4 * 16 + g * 4 + r;
            const float e = EXP2F(sa[r] * SCALE);
            pv[t4][r] = (key <= q) ? e : 0.f;
          }
        } else {
#pragma unroll
          for (int r = 0; r < 4; ++r) pv[t4][r] = EXP2F(sa[r] * SCALE);
        }
      }
      float lsum = 0.f;
#pragma unroll
      for (int t4 = 0; t4 < 4; ++t4)
        lsum += (pv[t4][0] + pv[t4][1]) + (pv[t4][2] + pv[t4][3]);
      l1 += lsum;

#pragma unroll
      for (int t4 = 0; t4 < 4; ++t4) {
        union { unsigned u[2]; shortx4 v; } pk;
        pk.u[0] = pack_bf2(pv[t4][0], pv[t4][1]);
        pk.u[1] = pack_bf2(pv[t4][2], pv[t4][3]);
        const int cc = t4 * 2 + (g >> 1);
        const int ko = (g & 1) * 4;
#pragma unroll
        for (int td = 0; td < 4; ++td) {
          const shortx4 va = *reinterpret_cast<const shortx4*>(
              &Vc[(td * 16 + c) * 64 + (cc ^ (c & 7)) * 8 + ko]);
          oacc1[td] = MFMA16K16(va, pk.v, oacc1[td]);
        }
      }
    }
    __builtin_amdgcn_s_barrier();   // all waves done reading buf[cur] before
                                    // next iter's stage overwrites it
  }

  // l: reduce across quads (q = c; partial per quad g) then normalize+store
#pragma unroll
  for (int grp = 0; grp < 2; ++grp) {
    float ls = (grp == 0) ? l0 : l1;
    ls += __shfl_xor(ls, 16, 64);
    ls += __shfl_xor(ls, 32, 64);
    const float inv = 1.f / ls;
    const int q = ((grp == 0) ? rb0 : rb1) + c;
    ushort_t* ob = &obuf[((size_t)(b * 2048 + q) * 16 + h) * 64];
#pragma unroll
    for (int td = 0; td < 4; ++td) {
      const floatx4 oa = (grp == 0) ? oacc0[td] : oacc1[td];
      ushortx4 pk;
#pragma unroll
      for (int r = 0; r < 4; ++r) pk[r] = f2bfu(oa[r] * inv);
      *reinterpret_cast<ushortx4*>(&ob[td * 16 + g * 4]) = pk;
    }
  }
}

// ---------------------------------------------------------------------------
// Output projection: out[m,n] = sum_k O[m,k] * Wp[n,k] + bp[n], fp32 out.
// R9 body. XCD remap as in gemm_qkv.
// ---------------------------------------------------------------------------
__global__ __launch_bounds__(256) void gemm_proj(
    const ushort_t* __restrict__ A, const ushort_t* __restrict__ Wp,
    const float* __restrict__ bias, float* __restrict__ out)
{
  const int L = (int)(blockIdx.x + 64 * blockIdx.y);  // grid (64,8), L in [0,512)
  const int rr = L & 7, mm = L >> 3;                  // mm 0..63
  const int m0 = (rr + 8 * (mm & 7)) * 128;
  const int n0 = (mm >> 3) * 128;

  __shared__ ushort_t Al[128 * 64];
  __shared__ ushort_t Bl[128 * 64];
  const int tid = threadIdx.x;
  const int w = tid >> 6, lane = tid & 63, g = lane >> 4, c = lane & 15;
  const int wm = w >> 1, wn = w & 1;
  const int cswz = c & 7;

  floatx4 acc[4][4];
  const floatx4 zero4 = {0.f, 0.f, 0.f, 0.f};
#pragma unroll
  for (int i = 0; i < 4; ++i)
#pragma unroll
    for (int j = 0; j < 4; ++j) acc[i][j] = zero4;

  const int srow = tid >> 3;
  const int gsw  = ((tid & 7) ^ (srow & 7)) * 8;

  for (int k0 = 0; k0 < 1024; k0 += 64) {
#pragma unroll
    for (int p = 0; p < 4; ++p) {
      const int row = p * 32 + srow;
      gl_lds16(&A [(size_t)(m0 + row) * 1024 + k0 + gsw], &Al[p * 2048 + tid * 8]);
      gl_lds16(&Wp[(size_t)(n0 + row) * 1024 + k0 + gsw], &Bl[p * 2048 + tid * 8]);
    }
    __syncthreads();
#pragma unroll
    for (int kk = 0; kk < 2; ++kk) {
      bf16x8 af[4], bfr[4];
#pragma unroll
      for (int i = 0; i < 4; ++i) {
        const int sw = ((kk * 4 + g) ^ cswz) * 8;
        af[i]  = *reinterpret_cast<const bf16x8*>(&Al[(wm * 64 + i * 16 + c) * 64 + sw]);
        bfr[i] = *reinterpret_cast<const bf16x8*>(&Bl[(wn * 64 + i * 16 + c) * 64 + sw]);
      }
#pragma unroll
      for (int i = 0; i < 4; ++i)
#pragma unroll
        for (int j = 0; j < 4; ++j)
          acc[i][j] = MFMA16(af[i], bfr[j], acc[i][j]);
    }
    __syncthreads();
  }

#pragma unroll
  for (int i = 0; i < 4; ++i) {
#pragma unroll
    for (int j = 0; j < 4; ++j) {
      const int n = n0 + wn * 64 + j * 16 + c;
      const float bv = bias[n];
#pragma unroll
      for (int r = 0; r < 4; ++r) {
        const int m = m0 + wm * 64 + i * 16 + g * 4 + r;
        out[(size_t)m * 1024 + n] = acc[i][j][r] + bv;
      }
    }
  }
}

extern "C" void kernel_launch(void* const* d_in, const int* in_sizes, int n_in,
                              void* d_out, int out_size, void* d_ws, size_t ws_size,
                              hipStream_t stream) {
  const float* x  = (const float*)d_in[0];
  const float* Wk = (const float*)d_in[1];   // input order: x, Wk, Wq, Wv, Wp, bp
  const float* Wq = (const float*)d_in[2];
  const float* Wv = (const float*)d_in[3];
  const float* Wp = (const float*)d_in[4];
  const float* bp = (const float*)d_in[5];
  float* out = (float*)d_out;

  char* ws = (char*)d_ws;
  const size_t SZ_X = (size_t)8192 * 1024 * 2;  // 16 MB bf16
  const size_t SZ_W = (size_t)1024 * 1024 * 2;  //  2 MB bf16
  ushort_t* xb    = (ushort_t*)ws;  ws += SZ_X;  // xb..wpb contiguous (cvt_all dst)
  ushort_t* wkb   = (ushort_t*)ws;  ws += SZ_W;
  ushort_t* wqb   = (ushort_t*)ws;  ws += SZ_W;
  ushort_t* wvb   = (ushort_t*)ws;  ws += SZ_W;
  ushort_t* wpb   = (ushort_t*)ws;  ws += SZ_W;
  ushort_t* qbuf  = (ushort_t*)ws;  ws += SZ_X;
  ushort_t* kbuf  = (ushort_t*)ws;  ws += SZ_X;
  ushort_t* vtbuf = (ushort_t*)ws;  ws += SZ_X;
  ushort_t* obuf  = xb;  // x is consumed by gemm_qkv before attn writes obuf

  cvt_all<<<12288, 256, 0, stream>>>(x, Wk, Wq, Wv, Wp, (ushortx4*)xb);

  gemm_qkv<<<dim3(64, 8, 3), 256, 0, stream>>>(xb, wqb, wkb, wvb, qbuf, kbuf, vtbuf);
  attn_kernel<<<dim3(16, 16, 4), 256, 0, stream>>>(qbuf, kbuf, vtbuf, obuf);
  gemm_proj<<<dim3(64, 8), 256, 0, stream>>>(obuf, wpb, bp, out);
}

// Round 6
// 242.389 us; speedup vs baseline: 1.0429x; 1.0350x over previous
//
#include <hip/hip_runtime.h>
#include <hip/hip_bf16.h>
#include <stdint.h>

// ---------------------------------------------------------------------------
// MultiHeadAttention fused forward, bf16-MFMA pipeline.
// B=4, T=2048, D=1024, H=16, HD=64.  Input order: x, Wk, Wq, Wv, Wp, bp (fp32).
// R15: attn reverted byte-exact to R12 body (R14's K/V-frag dedup regressed
//      attn 57->75us despite removing 25% of LDS reads — codegen pathology,
//      unreproducible without disasm; restructures keep losing, only additive
//      schedule changes have won). Single additive change on top of R12:
//      s_setprio(1) during attn compute phase / (0) during stage+barrier
//      (T5; m191 attn precedent — 4 independent blocks/CU at different
//      phases give the scheduler role diversity to arbitrate).
//      gemm_qkv/gemm_proj/cvt = R9 bodies (proven).
// ---------------------------------------------------------------------------

typedef __bf16 bf16x8 __attribute__((ext_vector_type(8)));
typedef float floatx4 __attribute__((ext_vector_type(4)));
typedef unsigned short ushort_t;
typedef unsigned short ushortx8 __attribute__((ext_vector_type(8)));
typedef unsigned short ushortx4 __attribute__((ext_vector_type(4)));
typedef short shortx4 __attribute__((ext_vector_type(4)));

#define MFMA16(a, b, c) __builtin_amdgcn_mfma_f32_16x16x32_bf16((a), (b), (c), 0, 0, 0)
#define MFMA16K16(a, b, c) __builtin_amdgcn_mfma_f32_16x16x16bf16_1k((a), (b), (c), 0, 0, 0)
#define EXP2F(x) __builtin_amdgcn_exp2f(x)

static __device__ __forceinline__ ushort_t f2bfu(float f) {
  union { float f; unsigned u; } v; v.f = f;
  unsigned r = v.u + 0x7FFFu + ((v.u >> 16) & 1u);  // RNE
  return (ushort_t)(r >> 16);
}

// pack two floats' bf16-truncations into one dword: (hi<<16)|lo
static __device__ __forceinline__ unsigned pack_bf2(float lo, float hi) {
  return __builtin_amdgcn_perm(__float_as_uint(hi), __float_as_uint(lo), 0x07060302);
}

// async 16B global -> LDS DMA (dest is wave-uniform base + lane*16)
static __device__ __forceinline__ void gl_lds16(const void* g, void* l) {
  __builtin_amdgcn_global_load_lds(
      (const __attribute__((address_space(1))) void*)g,
      (__attribute__((address_space(3))) void*)l, 16, 0, 0);
}

// ---- fp32 -> bf16 cast, all 5 tensors in one launch (dst regions contiguous)
__global__ void cvt_all(const float* __restrict__ x,  const float* __restrict__ wk,
                        const float* __restrict__ wq, const float* __restrict__ wv,
                        const float* __restrict__ wp, ushortx4* __restrict__ dst) {
  const int i = blockIdx.x * blockDim.x + threadIdx.x;  // float4 units
  const float4* src; int off;
  if (i < 2097152) { src = (const float4*)x; off = i; }
  else {
    const int r = i - 2097152;
    const int sel = r >> 18;                 // 262144 float4 per weight
    off = r & 262143;
    src = (const float4*)(sel == 0 ? wk : sel == 1 ? wq : sel == 2 ? wv : wp);
  }
  const float4 f = src[off];
  ushortx4 o;
  o[0] = f2bfu(f.x); o[1] = f2bfu(f.y); o[2] = f2bfu(f.z); o[3] = f2bfu(f.w);
  dst[i] = o;
}

// ---------------------------------------------------------------------------
// QKV GEMM: C[m,n] = sum_k X[m,k] * W[n,k]   (M=8192, N=1024, K=1024)
// R9 body: 128x128 tile, m97 structure + XOR bank swizzle. z=0->Q, z=1->K,
// z=2->V^T. XCD remap: same m0 -> same linear%8 -> same XCD L2.
// ---------------------------------------------------------------------------
__global__ __launch_bounds__(256) void gemm_qkv(
    const ushort_t* __restrict__ X,
    const ushort_t* __restrict__ Wq, const ushort_t* __restrict__ Wk,
    const ushort_t* __restrict__ Wv,
    ushort_t* __restrict__ qb, ushort_t* __restrict__ kb, ushort_t* __restrict__ vtb)
{
  // XCD-aware relabel of (m0, n0, z): grid (64,8,3) flat L in [0,1536)
  const int L = (int)(blockIdx.x + 64 * (blockIdx.y + 8 * blockIdx.z));
  const int rr = L & 7, mm = L >> 3;           // mm 0..191
  const int m0 = (rr + 8 * (mm & 7)) * 128;    // 64 m-tiles, same tile -> same rr
  const int rest = mm >> 3;                    // 0..23
  const int n0 = (rest & 7) * 128;
  const int z = rest >> 3;

  const ushort_t* Bm = (z == 0) ? Wq : (z == 1) ? Wk : Wv;
  __shared__ ushort_t Al[128 * 64];
  __shared__ ushort_t Bl[128 * 64];
  const int tid = threadIdx.x;
  const int w = tid >> 6, lane = tid & 63, g = lane >> 4, c = lane & 15;
  const int wm = w >> 1, wn = w & 1;
  const int cswz = c & 7;

  floatx4 acc[4][4];
  const floatx4 zero4 = {0.f, 0.f, 0.f, 0.f};
#pragma unroll
  for (int i = 0; i < 4; ++i)
#pragma unroll
    for (int j = 0; j < 4; ++j) acc[i][j] = zero4;

  const int srow = tid >> 3;
  const int gsw  = ((tid & 7) ^ (srow & 7)) * 8;  // swizzled source chunk (shorts)

  for (int k0 = 0; k0 < 1024; k0 += 64) {
#pragma unroll
    for (int p = 0; p < 4; ++p) {
      const int row = p * 32 + srow;
      gl_lds16(&X [(size_t)(m0 + row) * 1024 + k0 + gsw], &Al[p * 2048 + tid * 8]);
      gl_lds16(&Bm[(size_t)(n0 + row) * 1024 + k0 + gsw], &Bl[p * 2048 + tid * 8]);
    }
    __syncthreads();
#pragma unroll
    for (int kk = 0; kk < 2; ++kk) {
      bf16x8 af[4], bfr[4];
#pragma unroll
      for (int i = 0; i < 4; ++i) {
        const int sw = ((kk * 4 + g) ^ cswz) * 8;
        af[i]  = *reinterpret_cast<const bf16x8*>(&Al[(wm * 64 + i * 16 + c) * 64 + sw]);
        bfr[i] = *reinterpret_cast<const bf16x8*>(&Bl[(wn * 64 + i * 16 + c) * 64 + sw]);
      }
#pragma unroll
      for (int i = 0; i < 4; ++i)
#pragma unroll
        for (int j = 0; j < 4; ++j)
          acc[i][j] = MFMA16(af[i], bfr[j], acc[i][j]);
    }
    __syncthreads();
  }

  // Epilogue: C/D layout row = g*4+r, col = c within each 16x16 tile.
#pragma unroll
  for (int i = 0; i < 4; ++i) {
#pragma unroll
    for (int j = 0; j < 4; ++j) {
      const int mbase = m0 + wm * 64 + i * 16 + g * 4;
      const int n = n0 + wn * 64 + j * 16 + c;
      const int h = n >> 6, d = n & 63;
      if (z == 2) {
        // V^T: [(bb*16+h)*64+d]*2048 + t, 4 consecutive t -> 8B store
        const int bb = mbase >> 11, t = mbase & 2047;
        ushortx4 pk;
#pragma unroll
        for (int r = 0; r < 4; ++r) pk[r] = f2bfu(acc[i][j][r]);
        *reinterpret_cast<ushortx4*>(&vtb[(size_t)((bb * 16 + h) * 64 + d) * 2048 + t]) = pk;
      } else {
        ushort_t* ob = (z == 0) ? qb : kb;
#pragma unroll
        for (int r = 0; r < 4; ++r) {
          const int m = mbase + r;
          const int bb = m >> 11, t = m & 2047;
          ob[(size_t)((bb * 16 + h) * 2048 + t) * 64 + d] = f2bfu(acc[i][j][r]);
        }
      }
    }
  }
}

// ---------------------------------------------------------------------------
// Flash attention (causal), register-resident P^T (R12 body, byte-exact,
// + setprio toggles at the phase boundaries).
// 64-key tiles, double-buffered K/V staging, prefetch-before-compute,
// counted s_waitcnt vmcnt(4) + raw barrier per tile.
// ---------------------------------------------------------------------------
__global__ __launch_bounds__(256, 4) void attn_kernel(
    const ushort_t* __restrict__ qbuf, const ushort_t* __restrict__ kbuf,
    const ushort_t* __restrict__ vtbuf, ushort_t* __restrict__ obuf)
{
  // XCD-aware relabel: grid (16,16,4) flat L in [0,1024)
  const int L = (int)(blockIdx.x + 16 * (blockIdx.y + 16 * blockIdx.z));
  const int rr = L & 7, mm = L >> 3;        // mm 0..127
  const int j = mm >> 3;                    // q-tile pair index 0..15
  const int bhl = rr * 8 + (mm & 7);        // 0..63, same bh -> same rr
  const int h = bhl & 15, b = bhl >> 4;

  const int tid = threadIdx.x, w = tid >> 6, lane = tid & 63, g = lane >> 4, c = lane & 15;

  __shared__ ushort_t Kl[2][64 * 64];     // [buf][key][d], XOR-swizzled 8-chunk rows
  __shared__ ushort_t Vl[2][64 * 64];     // [buf][d][key], XOR-swizzled 8-chunk rows

  const size_t bh = (size_t)(b * 16 + h);
  const ushort_t* kb_bh = kbuf + bh * 2048 * 64;
  const ushort_t* vt_bh = vtbuf + bh * 64 * 2048;
  const ushort_t* qb_bh = qbuf + bh * 2048 * 64;

  const int rb0 = j * 64 + w * 16;           // grp 0 q-rows (diag tile j)
  const int rb1 = (31 - j) * 64 + w * 16;    // grp 1 q-rows (diag tile 31-j)

  // Q B-frags (x32): B[n=q=lane&15][k=d=quad*8+j]: contiguous 16B loads
  bf16x8 aq0[2], aq1[2];
  {
    const ushort_t* qp0 = qb_bh + (size_t)(rb0 + c) * 64;
    aq0[0] = *reinterpret_cast<const bf16x8*>(qp0 + g * 8);
    aq0[1] = *reinterpret_cast<const bf16x8*>(qp0 + 32 + g * 8);
    const ushort_t* qp1 = qb_bh + (size_t)(rb1 + c) * 64;
    aq1[0] = *reinterpret_cast<const bf16x8*>(qp1 + g * 8);
    aq1[1] = *reinterpret_cast<const bf16x8*>(qp1 + 32 + g * 8);
  }

  // O^T accumulators: [grp][td] tile, lane holds d = td*16+g*4+r, q = rb+c
  floatx4 oacc0[4], oacc1[4];
  float l0 = 0.f, l1 = 0.f;
  const floatx4 zero4 = {0.f, 0.f, 0.f, 0.f};
#pragma unroll
  for (int td = 0; td < 4; ++td) { oacc0[td] = zero4; oacc1[td] = zero4; }

  // staging helpers: 2 passes x 32 rows x (8 lanes * 16B) per 64x64 tile
  const int srow8 = tid >> 3;                        // 0..31
  const int gswz  = ((tid & 7) ^ (srow8 & 7)) * 8;   // swizzled source chunk (shorts)

  const float SCALE = 0.18033688011112042f;  // 0.125 * log2(e)

  const int NT = 32 - j;   // 64-key subtiles needed (grp1 lim = 31-j)

  auto stage = [&](int ti, int buf) {        // 4 gl_lds per thread
    const int key0 = ti * 64;
#pragma unroll
    for (int p = 0; p < 2; ++p) {
      gl_lds16(&kb_bh[(size_t)(key0 + p * 32 + srow8) * 64 + gswz],
               &Kl[buf][p * 2048 + tid * 8]);
      gl_lds16(&vt_bh[(size_t)(p * 32 + srow8) * 2048 + key0 + gswz],
               &Vl[buf][p * 2048 + tid * 8]);
    }
  };

  stage(0, 0);

  for (int ti = 0; ti < NT; ++ti) {
    const int cur = ti & 1;
    if (ti + 1 < NT) {
      stage(ti + 1, cur ^ 1);                         // prefetch next tile
      asm volatile("s_waitcnt vmcnt(4)" ::: "memory"); // this tile's 4 landed
    } else {
      asm volatile("s_waitcnt vmcnt(0)" ::: "memory");
    }
    __builtin_amdgcn_s_barrier();
    __builtin_amdgcn_s_setprio(1);   // compute phase: outcompete staging waves

    const ushort_t* Kc = Kl[cur];
    const ushort_t* Vc = Vl[cur];
    const int key0s = ti * 64;

#pragma unroll
    for (int grp = 0; grp < 2; ++grp) {
      const int lim = (grp == 0) ? j : 31 - j;
      if (ti > lim) continue;        // uniform scalar branch
      const int rb = (grp == 0) ? rb0 : rb1;
      const bf16x8 b0 = (grp == 0) ? aq0[0] : aq1[0];
      const bf16x8 b1 = (grp == 0) ? aq0[1] : aq1[1];

      float pv[4][4];
#pragma unroll
      for (int t4 = 0; t4 < 4; ++t4) {
        // S^T tile: A = K-frag (m=key=lane&15 -> row key0s+t4*16+c)
        const int krow = t4 * 16 + c;
        const bf16x8 k0f = *reinterpret_cast<const bf16x8*>(&Kc[krow * 64 + ((g) ^ (c & 7)) * 8]);
        const bf16x8 k1f = *reinterpret_cast<const bf16x8*>(&Kc[krow * 64 + ((4 + g) ^ (c & 7)) * 8]);
        floatx4 sa = zero4;
        sa = MFMA16(k0f, b0, sa);
        sa = MFMA16(k1f, b1, sa);
        // C/D: lane c = q-col, reg r -> key = key0s + t4*16 + g*4 + r
        if (ti == lim) {             // diagonal tile: causal mask
          const int q = rb + c;
#pragma unroll
          for (int r = 0; r < 4; ++r) {
            const int key = key0s + t4 * 16 + g * 4 + r;
            const float e = EXP2F(sa[r] * SCALE);
            pv[t4][r] = (key <= q) ? e : 0.f;
          }
        } else {
#pragma unroll
          for (int r = 0; r < 4; ++r) pv[t4][r] = EXP2F(sa[r] * SCALE);
        }
      }
      // l partial (each lane's 16 values all belong to q = rb+c)
      float lsum = 0.f;
#pragma unroll
      for (int t4 = 0; t4 < 4; ++t4)
        lsum += (pv[t4][0] + pv[t4][1]) + (pv[t4][2] + pv[t4][3]);
      if (grp == 0) l0 += lsum; else l1 += lsum;

      // PV: O^T += V^T * P^T via mfma 16x16x16 (P^T regs ARE the B-frag)
#pragma unroll
      for (int t4 = 0; t4 < 4; ++t4) {
        union { unsigned u[2]; shortx4 v; } pk;
        pk.u[0] = pack_bf2(pv[t4][0], pv[t4][1]);
        pk.u[1] = pack_bf2(pv[t4][2], pv[t4][3]);
        const int cc = t4 * 2 + (g >> 1);              // V key-chunk index (0..7)
        const int ko = (g & 1) * 4;                    // within-chunk key
#pragma unroll
        for (int td = 0; td < 4; ++td) {
          const shortx4 va = *reinterpret_cast<const shortx4*>(
              &Vc[(td * 16 + c) * 64 + (cc ^ (c & 7)) * 8 + ko]);
          if (grp == 0) oacc0[td] = MFMA16K16(va, pk.v, oacc0[td]);
          else          oacc1[td] = MFMA16K16(va, pk.v, oacc1[td]);
        }
      }
    }
    __builtin_amdgcn_s_setprio(0);  // back to stage/barrier phase
    __builtin_amdgcn_s_barrier();   // all waves done reading buf[cur] before
                                    // next iter's stage overwrites it
  }

  // l: reduce across quads (q = c; partial per quad g) then normalize+store
#pragma unroll
  for (int grp = 0; grp < 2; ++grp) {
    float ls = (grp == 0) ? l0 : l1;
    ls += __shfl_xor(ls, 16, 64);
    ls += __shfl_xor(ls, 32, 64);
    const float inv = 1.f / ls;
    const int q = ((grp == 0) ? rb0 : rb1) + c;
    ushort_t* ob = &obuf[((size_t)(b * 2048 + q) * 16 + h) * 64];
#pragma unroll
    for (int td = 0; td < 4; ++td) {
      const floatx4 oa = (grp == 0) ? oacc0[td] : oacc1[td];
      ushortx4 pk;
#pragma unroll
      for (int r = 0; r < 4; ++r) pk[r] = f2bfu(oa[r] * inv);
      *reinterpret_cast<ushortx4*>(&ob[td * 16 + g * 4]) = pk;
    }
  }
}

// ---------------------------------------------------------------------------
// Output projection: out[m,n] = sum_k O[m,k] * Wp[n,k] + bp[n], fp32 out.
// R9 body. XCD remap as in gemm_qkv.
// ---------------------------------------------------------------------------
__global__ __launch_bounds__(256) void gemm_proj(
    const ushort_t* __restrict__ A, const ushort_t* __restrict__ Wp,
    const float* __restrict__ bias, float* __restrict__ out)
{
  const int L = (int)(blockIdx.x + 64 * blockIdx.y);  // grid (64,8), L in [0,512)
  const int rr = L & 7, mm = L >> 3;                  // mm 0..63
  const int m0 = (rr + 8 * (mm & 7)) * 128;
  const int n0 = (mm >> 3) * 128;

  __shared__ ushort_t Al[128 * 64];
  __shared__ ushort_t Bl[128 * 64];
  const int tid = threadIdx.x;
  const int w = tid >> 6, lane = tid & 63, g = lane >> 4, c = lane & 15;
  const int wm = w >> 1, wn = w & 1;
  const int cswz = c & 7;

  floatx4 acc[4][4];
  const floatx4 zero4 = {0.f, 0.f, 0.f, 0.f};
#pragma unroll
  for (int i = 0; i < 4; ++i)
#pragma unroll
    for (int j = 0; j < 4; ++j) acc[i][j] = zero4;

  const int srow = tid >> 3;
  const int gsw  = ((tid & 7) ^ (srow & 7)) * 8;

  for (int k0 = 0; k0 < 1024; k0 += 64) {
#pragma unroll
    for (int p = 0; p < 4; ++p) {
      const int row = p * 32 + srow;
      gl_lds16(&A [(size_t)(m0 + row) * 1024 + k0 + gsw], &Al[p * 2048 + tid * 8]);
      gl_lds16(&Wp[(size_t)(n0 + row) * 1024 + k0 + gsw], &Bl[p * 2048 + tid * 8]);
    }
    __syncthreads();
#pragma unroll
    for (int kk = 0; kk < 2; ++kk) {
      bf16x8 af[4], bfr[4];
#pragma unroll
      for (int i = 0; i < 4; ++i) {
        const int sw = ((kk * 4 + g) ^ cswz) * 8;
        af[i]  = *reinterpret_cast<const bf16x8*>(&Al[(wm * 64 + i * 16 + c) * 64 + sw]);
        bfr[i] = *reinterpret_cast<const bf16x8*>(&Bl[(wn * 64 + i * 16 + c) * 64 + sw]);
      }
#pragma unroll
      for (int i = 0; i < 4; ++i)
#pragma unroll
        for (int j = 0; j < 4; ++j)
          acc[i][j] = MFMA16(af[i], bfr[j], acc[i][j]);
    }
    __syncthreads();
  }

#pragma unroll
  for (int i = 0; i < 4; ++i) {
#pragma unroll
    for (int j = 0; j < 4; ++j) {
      const int n = n0 + wn * 64 + j * 16 + c;
      const float bv = bias[n];
#pragma unroll
      for (int r = 0; r < 4; ++r) {
        const int m = m0 + wm * 64 + i * 16 + g * 4 + r;
        out[(size_t)m * 1024 + n] = acc[i][j][r] + bv;
      }
    }
  }
}

extern "C" void kernel_launch(void* const* d_in, const int* in_sizes, int n_in,
                              void* d_out, int out_size, void* d_ws, size_t ws_size,
                              hipStream_t stream) {
  const float* x  = (const float*)d_in[0];
  const float* Wk = (const float*)d_in[1];   // input order: x, Wk, Wq, Wv, Wp, bp
  const float* Wq = (const float*)d_in[2];
  const float* Wv = (const float*)d_in[3];
  const float* Wp = (const float*)d_in[4];
  const float* bp = (const float*)d_in[5];
  float* out = (float*)d_out;

  char* ws = (char*)d_ws;
  const size_t SZ_X = (size_t)8192 * 1024 * 2;  // 16 MB bf16
  const size_t SZ_W = (size_t)1024 * 1024 * 2;  //  2 MB bf16
  ushort_t* xb    = (ushort_t*)ws;  ws += SZ_X;  // xb..wpb contiguous (cvt_all dst)
  ushort_t* wkb   = (ushort_t*)ws;  ws += SZ_W;
  ushort_t* wqb   = (ushort_t*)ws;  ws += SZ_W;
  ushort_t* wvb   = (ushort_t*)ws;  ws += SZ_W;
  ushort_t* wpb   = (ushort_t*)ws;  ws += SZ_W;
  ushort_t* qbuf  = (ushort_t*)ws;  ws += SZ_X;
  ushort_t* kbuf  = (ushort_t*)ws;  ws += SZ_X;
  ushort_t* vtbuf = (ushort_t*)ws;  ws += SZ_X;
  ushort_t* obuf  = xb;  // x is consumed by gemm_qkv before attn writes obuf

  cvt_all<<<12288, 256, 0, stream>>>(x, Wk, Wq, Wv, Wp, (ushortx4*)xb);

  gemm_qkv<<<dim3(64, 8, 3), 256, 0, stream>>>(xb, wqb, wkb, wvb, qbuf, kbuf, vtbuf);
  attn_kernel<<<dim3(16, 16, 4), 256, 0, stream>>>(qbuf, kbuf, vtbuf, obuf);
  gemm_proj<<<dim3(64, 8), 256, 0, stream>>>(obuf, wpb, bp, out);
}

// Round 7
// 235.821 us; speedup vs baseline: 1.0720x; 1.0278x over previous
//
#include <hip/hip_runtime.h>
#include <hip/hip_bf16.h>
#include <stdint.h>

// ---------------------------------------------------------------------------
// MultiHeadAttention fused forward, bf16-MFMA pipeline.
// B=4, T=2048, D=1024, H=16, HD=64.  Input order: x, Wk, Wq, Wv, Wp, bp (fp32).
// R16: byte-exact R12 configuration (best verified: 231.7us) — qkv/proj = R9
//      bodies, attn = R12 double-buffered counted-vmcnt body WITHOUT setprio
//      (R15 showed setprio costs +10.7us here: barrier-locked waves within a
//      block = m190's negative case, not m191's).  Single change: cvt_all
//      grid-strided at 2048 blocks (G11) — 6 load/store pairs per thread for
//      per-thread MLP instead of 12288 one-shot micro-blocks.
// ---------------------------------------------------------------------------

typedef __bf16 bf16x8 __attribute__((ext_vector_type(8)));
typedef float floatx4 __attribute__((ext_vector_type(4)));
typedef unsigned short ushort_t;
typedef unsigned short ushortx8 __attribute__((ext_vector_type(8)));
typedef unsigned short ushortx4 __attribute__((ext_vector_type(4)));
typedef short shortx4 __attribute__((ext_vector_type(4)));

#define MFMA16(a, b, c) __builtin_amdgcn_mfma_f32_16x16x32_bf16((a), (b), (c), 0, 0, 0)
#define MFMA16K16(a, b, c) __builtin_amdgcn_mfma_f32_16x16x16bf16_1k((a), (b), (c), 0, 0, 0)
#define EXP2F(x) __builtin_amdgcn_exp2f(x)

static __device__ __forceinline__ ushort_t f2bfu(float f) {
  union { float f; unsigned u; } v; v.f = f;
  unsigned r = v.u + 0x7FFFu + ((v.u >> 16) & 1u);  // RNE
  return (ushort_t)(r >> 16);
}

// pack two floats' bf16-truncations into one dword: (hi<<16)|lo
static __device__ __forceinline__ unsigned pack_bf2(float lo, float hi) {
  return __builtin_amdgcn_perm(__float_as_uint(hi), __float_as_uint(lo), 0x07060302);
}

// async 16B global -> LDS DMA (dest is wave-uniform base + lane*16)
static __device__ __forceinline__ void gl_lds16(const void* g, void* l) {
  __builtin_amdgcn_global_load_lds(
      (const __attribute__((address_space(1))) void*)g,
      (__attribute__((address_space(3))) void*)l, 16, 0, 0);
}

// ---- fp32 -> bf16 cast, all 5 tensors in one launch (dst regions contiguous)
// R16: grid-stride at 2048 blocks (G11): 524288 threads x 6 iterations.
__global__ void cvt_all(const float* __restrict__ x,  const float* __restrict__ wk,
                        const float* __restrict__ wq, const float* __restrict__ wv,
                        const float* __restrict__ wp, ushortx4* __restrict__ dst) {
  const int tid0 = blockIdx.x * blockDim.x + threadIdx.x;  // float4 units
#pragma unroll
  for (int it = 0; it < 6; ++it) {
    const int i = tid0 + it * 524288;                      // 6*524288 = 3145728
    const float4* src; int off;
    if (i < 2097152) { src = (const float4*)x; off = i; }
    else {
      const int r = i - 2097152;
      const int sel = r >> 18;                 // 262144 float4 per weight
      off = r & 262143;
      src = (const float4*)(sel == 0 ? wk : sel == 1 ? wq : sel == 2 ? wv : wp);
    }
    const float4 f = src[off];
    ushortx4 o;
    o[0] = f2bfu(f.x); o[1] = f2bfu(f.y); o[2] = f2bfu(f.z); o[3] = f2bfu(f.w);
    dst[i] = o;
  }
}

// ---------------------------------------------------------------------------
// QKV GEMM: C[m,n] = sum_k X[m,k] * W[n,k]   (M=8192, N=1024, K=1024)
// R9 body: 128x128 tile, m97 structure + XOR bank swizzle. z=0->Q, z=1->K,
// z=2->V^T. XCD remap: same m0 -> same linear%8 -> same XCD L2.
// ---------------------------------------------------------------------------
__global__ __launch_bounds__(256) void gemm_qkv(
    const ushort_t* __restrict__ X,
    const ushort_t* __restrict__ Wq, const ushort_t* __restrict__ Wk,
    const ushort_t* __restrict__ Wv,
    ushort_t* __restrict__ qb, ushort_t* __restrict__ kb, ushort_t* __restrict__ vtb)
{
  // XCD-aware relabel of (m0, n0, z): grid (64,8,3) flat L in [0,1536)
  const int L = (int)(blockIdx.x + 64 * (blockIdx.y + 8 * blockIdx.z));
  const int rr = L & 7, mm = L >> 3;           // mm 0..191
  const int m0 = (rr + 8 * (mm & 7)) * 128;    // 64 m-tiles, same tile -> same rr
  const int rest = mm >> 3;                    // 0..23
  const int n0 = (rest & 7) * 128;
  const int z = rest >> 3;

  const ushort_t* Bm = (z == 0) ? Wq : (z == 1) ? Wk : Wv;
  __shared__ ushort_t Al[128 * 64];
  __shared__ ushort_t Bl[128 * 64];
  const int tid = threadIdx.x;
  const int w = tid >> 6, lane = tid & 63, g = lane >> 4, c = lane & 15;
  const int wm = w >> 1, wn = w & 1;
  const int cswz = c & 7;

  floatx4 acc[4][4];
  const floatx4 zero4 = {0.f, 0.f, 0.f, 0.f};
#pragma unroll
  for (int i = 0; i < 4; ++i)
#pragma unroll
    for (int j = 0; j < 4; ++j) acc[i][j] = zero4;

  const int srow = tid >> 3;
  const int gsw  = ((tid & 7) ^ (srow & 7)) * 8;  // swizzled source chunk (shorts)

  for (int k0 = 0; k0 < 1024; k0 += 64) {
#pragma unroll
    for (int p = 0; p < 4; ++p) {
      const int row = p * 32 + srow;
      gl_lds16(&X [(size_t)(m0 + row) * 1024 + k0 + gsw], &Al[p * 2048 + tid * 8]);
      gl_lds16(&Bm[(size_t)(n0 + row) * 1024 + k0 + gsw], &Bl[p * 2048 + tid * 8]);
    }
    __syncthreads();
#pragma unroll
    for (int kk = 0; kk < 2; ++kk) {
      bf16x8 af[4], bfr[4];
#pragma unroll
      for (int i = 0; i < 4; ++i) {
        const int sw = ((kk * 4 + g) ^ cswz) * 8;
        af[i]  = *reinterpret_cast<const bf16x8*>(&Al[(wm * 64 + i * 16 + c) * 64 + sw]);
        bfr[i] = *reinterpret_cast<const bf16x8*>(&Bl[(wn * 64 + i * 16 + c) * 64 + sw]);
      }
#pragma unroll
      for (int i = 0; i < 4; ++i)
#pragma unroll
        for (int j = 0; j < 4; ++j)
          acc[i][j] = MFMA16(af[i], bfr[j], acc[i][j]);
    }
    __syncthreads();
  }

  // Epilogue: C/D layout row = g*4+r, col = c within each 16x16 tile.
#pragma unroll
  for (int i = 0; i < 4; ++i) {
#pragma unroll
    for (int j = 0; j < 4; ++j) {
      const int mbase = m0 + wm * 64 + i * 16 + g * 4;
      const int n = n0 + wn * 64 + j * 16 + c;
      const int h = n >> 6, d = n & 63;
      if (z == 2) {
        // V^T: [(bb*16+h)*64+d]*2048 + t, 4 consecutive t -> 8B store
        const int bb = mbase >> 11, t = mbase & 2047;
        ushortx4 pk;
#pragma unroll
        for (int r = 0; r < 4; ++r) pk[r] = f2bfu(acc[i][j][r]);
        *reinterpret_cast<ushortx4*>(&vtb[(size_t)((bb * 16 + h) * 64 + d) * 2048 + t]) = pk;
      } else {
        ushort_t* ob = (z == 0) ? qb : kb;
#pragma unroll
        for (int r = 0; r < 4; ++r) {
          const int m = mbase + r;
          const int bb = m >> 11, t = m & 2047;
          ob[(size_t)((bb * 16 + h) * 2048 + t) * 64 + d] = f2bfu(acc[i][j][r]);
        }
      }
    }
  }
}

// ---------------------------------------------------------------------------
// Flash attention (causal), register-resident P^T (R12 body, byte-exact).
// 64-key tiles, double-buffered K/V staging, prefetch-before-compute,
// counted s_waitcnt vmcnt(4) + raw barrier per tile. NO setprio (R15: -10.7us).
// ---------------------------------------------------------------------------
__global__ __launch_bounds__(256, 4) void attn_kernel(
    const ushort_t* __restrict__ qbuf, const ushort_t* __restrict__ kbuf,
    const ushort_t* __restrict__ vtbuf, ushort_t* __restrict__ obuf)
{
  // XCD-aware relabel: grid (16,16,4) flat L in [0,1024)
  const int L = (int)(blockIdx.x + 16 * (blockIdx.y + 16 * blockIdx.z));
  const int rr = L & 7, mm = L >> 3;        // mm 0..127
  const int j = mm >> 3;                    // q-tile pair index 0..15
  const int bhl = rr * 8 + (mm & 7);        // 0..63, same bh -> same rr
  const int h = bhl & 15, b = bhl >> 4;

  const int tid = threadIdx.x, w = tid >> 6, lane = tid & 63, g = lane >> 4, c = lane & 15;

  __shared__ ushort_t Kl[2][64 * 64];     // [buf][key][d], XOR-swizzled 8-chunk rows
  __shared__ ushort_t Vl[2][64 * 64];     // [buf][d][key], XOR-swizzled 8-chunk rows

  const size_t bh = (size_t)(b * 16 + h);
  const ushort_t* kb_bh = kbuf + bh * 2048 * 64;
  const ushort_t* vt_bh = vtbuf + bh * 64 * 2048;
  const ushort_t* qb_bh = qbuf + bh * 2048 * 64;

  const int rb0 = j * 64 + w * 16;           // grp 0 q-rows (diag tile j)
  const int rb1 = (31 - j) * 64 + w * 16;    // grp 1 q-rows (diag tile 31-j)

  // Q B-frags (x32): B[n=q=lane&15][k=d=quad*8+j]: contiguous 16B loads
  bf16x8 aq0[2], aq1[2];
  {
    const ushort_t* qp0 = qb_bh + (size_t)(rb0 + c) * 64;
    aq0[0] = *reinterpret_cast<const bf16x8*>(qp0 + g * 8);
    aq0[1] = *reinterpret_cast<const bf16x8*>(qp0 + 32 + g * 8);
    const ushort_t* qp1 = qb_bh + (size_t)(rb1 + c) * 64;
    aq1[0] = *reinterpret_cast<const bf16x8*>(qp1 + g * 8);
    aq1[1] = *reinterpret_cast<const bf16x8*>(qp1 + 32 + g * 8);
  }

  // O^T accumulators: [grp][td] tile, lane holds d = td*16+g*4+r, q = rb+c
  floatx4 oacc0[4], oacc1[4];
  float l0 = 0.f, l1 = 0.f;
  const floatx4 zero4 = {0.f, 0.f, 0.f, 0.f};
#pragma unroll
  for (int td = 0; td < 4; ++td) { oacc0[td] = zero4; oacc1[td] = zero4; }

  // staging helpers: 2 passes x 32 rows x (8 lanes * 16B) per 64x64 tile
  const int srow8 = tid >> 3;                        // 0..31
  const int gswz  = ((tid & 7) ^ (srow8 & 7)) * 8;   // swizzled source chunk (shorts)

  const float SCALE = 0.18033688011112042f;  // 0.125 * log2(e)

  const int NT = 32 - j;   // 64-key subtiles needed (grp1 lim = 31-j)

  auto stage = [&](int ti, int buf) {        // 4 gl_lds per thread
    const int key0 = ti * 64;
#pragma unroll
    for (int p = 0; p < 2; ++p) {
      gl_lds16(&kb_bh[(size_t)(key0 + p * 32 + srow8) * 64 + gswz],
               &Kl[buf][p * 2048 + tid * 8]);
      gl_lds16(&vt_bh[(size_t)(p * 32 + srow8) * 2048 + key0 + gswz],
               &Vl[buf][p * 2048 + tid * 8]);
    }
  };

  stage(0, 0);

  for (int ti = 0; ti < NT; ++ti) {
    const int cur = ti & 1;
    if (ti + 1 < NT) {
      stage(ti + 1, cur ^ 1);                         // prefetch next tile
      asm volatile("s_waitcnt vmcnt(4)" ::: "memory"); // this tile's 4 landed
    } else {
      asm volatile("s_waitcnt vmcnt(0)" ::: "memory");
    }
    __builtin_amdgcn_s_barrier();

    const ushort_t* Kc = Kl[cur];
    const ushort_t* Vc = Vl[cur];
    const int key0s = ti * 64;

#pragma unroll
    for (int grp = 0; grp < 2; ++grp) {
      const int lim = (grp == 0) ? j : 31 - j;
      if (ti > lim) continue;        // uniform scalar branch
      const int rb = (grp == 0) ? rb0 : rb1;
      const bf16x8 b0 = (grp == 0) ? aq0[0] : aq1[0];
      const bf16x8 b1 = (grp == 0) ? aq0[1] : aq1[1];

      float pv[4][4];
#pragma unroll
      for (int t4 = 0; t4 < 4; ++t4) {
        // S^T tile: A = K-frag (m=key=lane&15 -> row key0s+t4*16+c)
        const int krow = t4 * 16 + c;
        const bf16x8 k0f = *reinterpret_cast<const bf16x8*>(&Kc[krow * 64 + ((g) ^ (c & 7)) * 8]);
        const bf16x8 k1f = *reinterpret_cast<const bf16x8*>(&Kc[krow * 64 + ((4 + g) ^ (c & 7)) * 8]);
        floatx4 sa = zero4;
        sa = MFMA16(k0f, b0, sa);
        sa = MFMA16(k1f, b1, sa);
        // C/D: lane c = q-col, reg r -> key = key0s + t4*16 + g*4 + r
        if (ti == lim) {             // diagonal tile: causal mask
          const int q = rb + c;
#pragma unroll
          for (int r = 0; r < 4; ++r) {
            const int key = key0s + t4 * 16 + g * 4 + r;
            const float e = EXP2F(sa[r] * SCALE);
            pv[t4][r] = (key <= q) ? e : 0.f;
          }
        } else {
#pragma unroll
          for (int r = 0; r < 4; ++r) pv[t4][r] = EXP2F(sa[r] * SCALE);
        }
      }
      // l partial (each lane's 16 values all belong to q = rb+c)
      float lsum = 0.f;
#pragma unroll
      for (int t4 = 0; t4 < 4; ++t4)
        lsum += (pv[t4][0] + pv[t4][1]) + (pv[t4][2] + pv[t4][3]);
      if (grp == 0) l0 += lsum; else l1 += lsum;

      // PV: O^T += V^T * P^T via mfma 16x16x16 (P^T regs ARE the B-frag)
#pragma unroll
      for (int t4 = 0; t4 < 4; ++t4) {
        union { unsigned u[2]; shortx4 v; } pk;
        pk.u[0] = pack_bf2(pv[t4][0], pv[t4][1]);
        pk.u[1] = pack_bf2(pv[t4][2], pv[t4][3]);
        const int cc = t4 * 2 + (g >> 1);              // V key-chunk index (0..7)
        const int ko = (g & 1) * 4;                    // within-chunk key
#pragma unroll
        for (int td = 0; td < 4; ++td) {
          const shortx4 va = *reinterpret_cast<const shortx4*>(
              &Vc[(td * 16 + c) * 64 + (cc ^ (c & 7)) * 8 + ko]);
          if (grp == 0) oacc0[td] = MFMA16K16(va, pk.v, oacc0[td]);
          else          oacc1[td] = MFMA16K16(va, pk.v, oacc1[td]);
        }
      }
    }
    __builtin_amdgcn_s_barrier();   // all waves done reading buf[cur] before
                                    // next iter's stage overwrites it
  }

  // l: reduce across quads (q = c; partial per quad g) then normalize+store
#pragma unroll
  for (int grp = 0; grp < 2; ++grp) {
    float ls = (grp == 0) ? l0 : l1;
    ls += __shfl_xor(ls, 16, 64);
    ls += __shfl_xor(ls, 32, 64);
    const float inv = 1.f / ls;
    const int q = ((grp == 0) ? rb0 : rb1) + c;
    ushort_t* ob = &obuf[((size_t)(b * 2048 + q) * 16 + h) * 64];
#pragma unroll
    for (int td = 0; td < 4; ++td) {
      const floatx4 oa = (grp == 0) ? oacc0[td] : oacc1[td];
      ushortx4 pk;
#pragma unroll
      for (int r = 0; r < 4; ++r) pk[r] = f2bfu(oa[r] * inv);
      *reinterpret_cast<ushortx4*>(&ob[td * 16 + g * 4]) = pk;
    }
  }
}

// ---------------------------------------------------------------------------
// Output projection: out[m,n] = sum_k O[m,k] * Wp[n,k] + bp[n], fp32 out.
// R9 body. XCD remap as in gemm_qkv.
// ---------------------------------------------------------------------------
__global__ __launch_bounds__(256) void gemm_proj(
    const ushort_t* __restrict__ A, const ushort_t* __restrict__ Wp,
    const float* __restrict__ bias, float* __restrict__ out)
{
  const int L = (int)(blockIdx.x + 64 * blockIdx.y);  // grid (64,8), L in [0,512)
  const int rr = L & 7, mm = L >> 3;                  // mm 0..63
  const int m0 = (rr + 8 * (mm & 7)) * 128;
  const int n0 = (mm >> 3) * 128;

  __shared__ ushort_t Al[128 * 64];
  __shared__ ushort_t Bl[128 * 64];
  const int tid = threadIdx.x;
  const int w = tid >> 6, lane = tid & 63, g = lane >> 4, c = lane & 15;
  const int wm = w >> 1, wn = w & 1;
  const int cswz = c & 7;

  floatx4 acc[4][4];
  const floatx4 zero4 = {0.f, 0.f, 0.f, 0.f};
#pragma unroll
  for (int i = 0; i < 4; ++i)
#pragma unroll
    for (int j = 0; j < 4; ++j) acc[i][j] = zero4;

  const int srow = tid >> 3;
  const int gsw  = ((tid & 7) ^ (srow & 7)) * 8;

  for (int k0 = 0; k0 < 1024; k0 += 64) {
#pragma unroll
    for (int p = 0; p < 4; ++p) {
      const int row = p * 32 + srow;
      gl_lds16(&A [(size_t)(m0 + row) * 1024 + k0 + gsw], &Al[p * 2048 + tid * 8]);
      gl_lds16(&Wp[(size_t)(n0 + row) * 1024 + k0 + gsw], &Bl[p * 2048 + tid * 8]);
    }
    __syncthreads();
#pragma unroll
    for (int kk = 0; kk < 2; ++kk) {
      bf16x8 af[4], bfr[4];
#pragma unroll
      for (int i = 0; i < 4; ++i) {
        const int sw = ((kk * 4 + g) ^ cswz) * 8;
        af[i]  = *reinterpret_cast<const bf16x8*>(&Al[(wm * 64 + i * 16 + c) * 64 + sw]);
        bfr[i] = *reinterpret_cast<const bf16x8*>(&Bl[(wn * 64 + i * 16 + c) * 64 + sw]);
      }
#pragma unroll
      for (int i = 0; i < 4; ++i)
#pragma unroll
        for (int j = 0; j < 4; ++j)
          acc[i][j] = MFMA16(af[i], bfr[j], acc[i][j]);
    }
    __syncthreads();
  }

#pragma unroll
  for (int i = 0; i < 4; ++i) {
#pragma unroll
    for (int j = 0; j < 4; ++j) {
      const int n = n0 + wn * 64 + j * 16 + c;
      const float bv = bias[n];
#pragma unroll
      for (int r = 0; r < 4; ++r) {
        const int m = m0 + wm * 64 + i * 16 + g * 4 + r;
        out[(size_t)m * 1024 + n] = acc[i][j][r] + bv;
      }
    }
  }
}

extern "C" void kernel_launch(void* const* d_in, const int* in_sizes, int n_in,
                              void* d_out, int out_size, void* d_ws, size_t ws_size,
                              hipStream_t stream) {
  const float* x  = (const float*)d_in[0];
  const float* Wk = (const float*)d_in[1];   // input order: x, Wk, Wq, Wv, Wp, bp
  const float* Wq = (const float*)d_in[2];
  const float* Wv = (const float*)d_in[3];
  const float* Wp = (const float*)d_in[4];
  const float* bp = (const float*)d_in[5];
  float* out = (float*)d_out;

  char* ws = (char*)d_ws;
  const size_t SZ_X = (size_t)8192 * 1024 * 2;  // 16 MB bf16
  const size_t SZ_W = (size_t)1024 * 1024 * 2;  //  2 MB bf16
  ushort_t* xb    = (ushort_t*)ws;  ws += SZ_X;  // xb..wpb contiguous (cvt_all dst)
  ushort_t* wkb   = (ushort_t*)ws;  ws += SZ_W;
  ushort_t* wqb   = (ushort_t*)ws;  ws += SZ_W;
  ushort_t* wvb   = (ushort_t*)ws;  ws += SZ_W;
  ushort_t* wpb   = (ushort_t*)ws;  ws += SZ_W;
  ushort_t* qbuf  = (ushort_t*)ws;  ws += SZ_X;
  ushort_t* kbuf  = (ushort_t*)ws;  ws += SZ_X;
  ushort_t* vtbuf = (ushort_t*)ws;  ws += SZ_X;
  ushort_t* obuf  = xb;  // x is consumed by gemm_qkv before attn writes obuf

  cvt_all<<<2048, 256, 0, stream>>>(x, Wk, Wq, Wv, Wp, (ushortx4*)xb);

  gemm_qkv<<<dim3(64, 8, 3), 256, 0, stream>>>(xb, wqb, wkb, wvb, qbuf, kbuf, vtbuf);
  attn_kernel<<<dim3(16, 16, 4), 256, 0, stream>>>(qbuf, kbuf, vtbuf, obuf);
  gemm_proj<<<dim3(64, 8), 256, 0, stream>>>(obuf, wpb, bp, out);
}

// Round 8
// 230.440 us; speedup vs baseline: 1.0970x; 1.0234x over previous
//
#include <hip/hip_runtime.h>
#include <hip/hip_bf16.h>
#include <stdint.h>

// ---------------------------------------------------------------------------
// MultiHeadAttention fused forward, bf16-MFMA pipeline.
// B=4, T=2048, D=1024, H=16, HD=64.  Input order: x, Wk, Wq, Wv, Wp, bp (fp32).
// R17 == R12 byte-exact (best verified: 231.7us). Ledger: every deviation
// regressed — R10/R11/R13 qkv 256-tile pipelines (72.9/73.7/82.1 vs 65.7),
// R14 attn LDS dedup (+19us codegen pathology), R15 setprio (+10.7us,
// barrier-locked waves = m190 negative case), R16 cvt grid-stride (+4.1us).
// Config: cvt 12288 one-shot blocks; gemm_qkv/gemm_proj = R9 m97-structure
// 128x128 XOR-swizzled gl_lds bodies; attn = 64-key double-buffered
// counted-vmcnt(4) prefetch-before-compute flash kernel.
// ---------------------------------------------------------------------------

typedef __bf16 bf16x8 __attribute__((ext_vector_type(8)));
typedef float floatx4 __attribute__((ext_vector_type(4)));
typedef unsigned short ushort_t;
typedef unsigned short ushortx8 __attribute__((ext_vector_type(8)));
typedef unsigned short ushortx4 __attribute__((ext_vector_type(4)));
typedef short shortx4 __attribute__((ext_vector_type(4)));

#define MFMA16(a, b, c) __builtin_amdgcn_mfma_f32_16x16x32_bf16((a), (b), (c), 0, 0, 0)
#define MFMA16K16(a, b, c) __builtin_amdgcn_mfma_f32_16x16x16bf16_1k((a), (b), (c), 0, 0, 0)
#define EXP2F(x) __builtin_amdgcn_exp2f(x)

static __device__ __forceinline__ ushort_t f2bfu(float f) {
  union { float f; unsigned u; } v; v.f = f;
  unsigned r = v.u + 0x7FFFu + ((v.u >> 16) & 1u);  // RNE
  return (ushort_t)(r >> 16);
}

// pack two floats' bf16-truncations into one dword: (hi<<16)|lo
static __device__ __forceinline__ unsigned pack_bf2(float lo, float hi) {
  return __builtin_amdgcn_perm(__float_as_uint(hi), __float_as_uint(lo), 0x07060302);
}

// async 16B global -> LDS DMA (dest is wave-uniform base + lane*16)
static __device__ __forceinline__ void gl_lds16(const void* g, void* l) {
  __builtin_amdgcn_global_load_lds(
      (const __attribute__((address_space(1))) void*)g,
      (__attribute__((address_space(3))) void*)l, 16, 0, 0);
}

// ---- fp32 -> bf16 cast, all 5 tensors in one launch (dst regions contiguous)
__global__ void cvt_all(const float* __restrict__ x,  const float* __restrict__ wk,
                        const float* __restrict__ wq, const float* __restrict__ wv,
                        const float* __restrict__ wp, ushortx4* __restrict__ dst) {
  const int i = blockIdx.x * blockDim.x + threadIdx.x;  // float4 units
  const float4* src; int off;
  if (i < 2097152) { src = (const float4*)x; off = i; }
  else {
    const int r = i - 2097152;
    const int sel = r >> 18;                 // 262144 float4 per weight
    off = r & 262143;
    src = (const float4*)(sel == 0 ? wk : sel == 1 ? wq : sel == 2 ? wv : wp);
  }
  const float4 f = src[off];
  ushortx4 o;
  o[0] = f2bfu(f.x); o[1] = f2bfu(f.y); o[2] = f2bfu(f.z); o[3] = f2bfu(f.w);
  dst[i] = o;
}

// ---------------------------------------------------------------------------
// QKV GEMM: C[m,n] = sum_k X[m,k] * W[n,k]   (M=8192, N=1024, K=1024)
// R9 body: 128x128 tile, m97 structure + XOR bank swizzle. z=0->Q, z=1->K,
// z=2->V^T. XCD remap: same m0 -> same linear%8 -> same XCD L2.
// ---------------------------------------------------------------------------
__global__ __launch_bounds__(256) void gemm_qkv(
    const ushort_t* __restrict__ X,
    const ushort_t* __restrict__ Wq, const ushort_t* __restrict__ Wk,
    const ushort_t* __restrict__ Wv,
    ushort_t* __restrict__ qb, ushort_t* __restrict__ kb, ushort_t* __restrict__ vtb)
{
  // XCD-aware relabel of (m0, n0, z): grid (64,8,3) flat L in [0,1536)
  const int L = (int)(blockIdx.x + 64 * (blockIdx.y + 8 * blockIdx.z));
  const int rr = L & 7, mm = L >> 3;           // mm 0..191
  const int m0 = (rr + 8 * (mm & 7)) * 128;    // 64 m-tiles, same tile -> same rr
  const int rest = mm >> 3;                    // 0..23
  const int n0 = (rest & 7) * 128;
  const int z = rest >> 3;

  const ushort_t* Bm = (z == 0) ? Wq : (z == 1) ? Wk : Wv;
  __shared__ ushort_t Al[128 * 64];
  __shared__ ushort_t Bl[128 * 64];
  const int tid = threadIdx.x;
  const int w = tid >> 6, lane = tid & 63, g = lane >> 4, c = lane & 15;
  const int wm = w >> 1, wn = w & 1;
  const int cswz = c & 7;

  floatx4 acc[4][4];
  const floatx4 zero4 = {0.f, 0.f, 0.f, 0.f};
#pragma unroll
  for (int i = 0; i < 4; ++i)
#pragma unroll
    for (int j = 0; j < 4; ++j) acc[i][j] = zero4;

  const int srow = tid >> 3;
  const int gsw  = ((tid & 7) ^ (srow & 7)) * 8;  // swizzled source chunk (shorts)

  for (int k0 = 0; k0 < 1024; k0 += 64) {
#pragma unroll
    for (int p = 0; p < 4; ++p) {
      const int row = p * 32 + srow;
      gl_lds16(&X [(size_t)(m0 + row) * 1024 + k0 + gsw], &Al[p * 2048 + tid * 8]);
      gl_lds16(&Bm[(size_t)(n0 + row) * 1024 + k0 + gsw], &Bl[p * 2048 + tid * 8]);
    }
    __syncthreads();
#pragma unroll
    for (int kk = 0; kk < 2; ++kk) {
      bf16x8 af[4], bfr[4];
#pragma unroll
      for (int i = 0; i < 4; ++i) {
        const int sw = ((kk * 4 + g) ^ cswz) * 8;
        af[i]  = *reinterpret_cast<const bf16x8*>(&Al[(wm * 64 + i * 16 + c) * 64 + sw]);
        bfr[i] = *reinterpret_cast<const bf16x8*>(&Bl[(wn * 64 + i * 16 + c) * 64 + sw]);
      }
#pragma unroll
      for (int i = 0; i < 4; ++i)
#pragma unroll
        for (int j = 0; j < 4; ++j)
          acc[i][j] = MFMA16(af[i], bfr[j], acc[i][j]);
    }
    __syncthreads();
  }

  // Epilogue: C/D layout row = g*4+r, col = c within each 16x16 tile.
#pragma unroll
  for (int i = 0; i < 4; ++i) {
#pragma unroll
    for (int j = 0; j < 4; ++j) {
      const int mbase = m0 + wm * 64 + i * 16 + g * 4;
      const int n = n0 + wn * 64 + j * 16 + c;
      const int h = n >> 6, d = n & 63;
      if (z == 2) {
        // V^T: [(bb*16+h)*64+d]*2048 + t, 4 consecutive t -> 8B store
        const int bb = mbase >> 11, t = mbase & 2047;
        ushortx4 pk;
#pragma unroll
        for (int r = 0; r < 4; ++r) pk[r] = f2bfu(acc[i][j][r]);
        *reinterpret_cast<ushortx4*>(&vtb[(size_t)((bb * 16 + h) * 64 + d) * 2048 + t]) = pk;
      } else {
        ushort_t* ob = (z == 0) ? qb : kb;
#pragma unroll
        for (int r = 0; r < 4; ++r) {
          const int m = mbase + r;
          const int bb = m >> 11, t = m & 2047;
          ob[(size_t)((bb * 16 + h) * 2048 + t) * 64 + d] = f2bfu(acc[i][j][r]);
        }
      }
    }
  }
}

// ---------------------------------------------------------------------------
// Flash attention (causal), register-resident P^T.
// 64-key tiles, double-buffered K/V staging (2 x 16 KiB each; total LDS
// 32 KiB -> 4 blocks/CU). Next tile's 4 gl_lds issued BEFORE compute;
// single s_waitcnt vmcnt(4) + s_barrier per tile.
// Block j of (b,h): q-tiles j and 31-j; wave w owns 16 rows of each.
// S^T = K*Q^T (C/D: lane=q, reg=key) -> P^T in registers == B-operand of
// mfma 16x16x16 -> O^T += V^T*P^T. Deferred l-reduction.
// ---------------------------------------------------------------------------
__global__ __launch_bounds__(256, 4) void attn_kernel(
    const ushort_t* __restrict__ qbuf, const ushort_t* __restrict__ kbuf,
    const ushort_t* __restrict__ vtbuf, ushort_t* __restrict__ obuf)
{
  // XCD-aware relabel: grid (16,16,4) flat L in [0,1024)
  const int L = (int)(blockIdx.x + 16 * (blockIdx.y + 16 * blockIdx.z));
  const int rr = L & 7, mm = L >> 3;        // mm 0..127
  const int j = mm >> 3;                    // q-tile pair index 0..15
  const int bhl = rr * 8 + (mm & 7);        // 0..63, same bh -> same rr
  const int h = bhl & 15, b = bhl >> 4;

  const int tid = threadIdx.x, w = tid >> 6, lane = tid & 63, g = lane >> 4, c = lane & 15;

  __shared__ ushort_t Kl[2][64 * 64];     // [buf][key][d], XOR-swizzled 8-chunk rows
  __shared__ ushort_t Vl[2][64 * 64];     // [buf][d][key], XOR-swizzled 8-chunk rows

  const size_t bh = (size_t)(b * 16 + h);
  const ushort_t* kb_bh = kbuf + bh * 2048 * 64;
  const ushort_t* vt_bh = vtbuf + bh * 64 * 2048;
  const ushort_t* qb_bh = qbuf + bh * 2048 * 64;

  const int rb0 = j * 64 + w * 16;           // grp 0 q-rows (diag tile j)
  const int rb1 = (31 - j) * 64 + w * 16;    // grp 1 q-rows (diag tile 31-j)

  // Q B-frags (x32): B[n=q=lane&15][k=d=quad*8+j]: contiguous 16B loads
  bf16x8 aq0[2], aq1[2];
  {
    const ushort_t* qp0 = qb_bh + (size_t)(rb0 + c) * 64;
    aq0[0] = *reinterpret_cast<const bf16x8*>(qp0 + g * 8);
    aq0[1] = *reinterpret_cast<const bf16x8*>(qp0 + 32 + g * 8);
    const ushort_t* qp1 = qb_bh + (size_t)(rb1 + c) * 64;
    aq1[0] = *reinterpret_cast<const bf16x8*>(qp1 + g * 8);
    aq1[1] = *reinterpret_cast<const bf16x8*>(qp1 + 32 + g * 8);
  }

  // O^T accumulators: [grp][td] tile, lane holds d = td*16+g*4+r, q = rb+c
  floatx4 oacc0[4], oacc1[4];
  float l0 = 0.f, l1 = 0.f;
  const floatx4 zero4 = {0.f, 0.f, 0.f, 0.f};
#pragma unroll
  for (int td = 0; td < 4; ++td) { oacc0[td] = zero4; oacc1[td] = zero4; }

  // staging helpers: 2 passes x 32 rows x (8 lanes * 16B) per 64x64 tile
  const int srow8 = tid >> 3;                        // 0..31
  const int gswz  = ((tid & 7) ^ (srow8 & 7)) * 8;   // swizzled source chunk (shorts)

  const float SCALE = 0.18033688011112042f;  // 0.125 * log2(e)

  const int NT = 32 - j;   // 64-key subtiles needed (grp1 lim = 31-j)

  auto stage = [&](int ti, int buf) {        // 4 gl_lds per thread
    const int key0 = ti * 64;
#pragma unroll
    for (int p = 0; p < 2; ++p) {
      gl_lds16(&kb_bh[(size_t)(key0 + p * 32 + srow8) * 64 + gswz],
               &Kl[buf][p * 2048 + tid * 8]);
      gl_lds16(&vt_bh[(size_t)(p * 32 + srow8) * 2048 + key0 + gswz],
               &Vl[buf][p * 2048 + tid * 8]);
    }
  };

  stage(0, 0);

  for (int ti = 0; ti < NT; ++ti) {
    const int cur = ti & 1;
    if (ti + 1 < NT) {
      stage(ti + 1, cur ^ 1);                         // prefetch next tile
      asm volatile("s_waitcnt vmcnt(4)" ::: "memory"); // this tile's 4 landed
    } else {
      asm volatile("s_waitcnt vmcnt(0)" ::: "memory");
    }
    __builtin_amdgcn_s_barrier();

    const ushort_t* Kc = Kl[cur];
    const ushort_t* Vc = Vl[cur];
    const int key0s = ti * 64;

#pragma unroll
    for (int grp = 0; grp < 2; ++grp) {
      const int lim = (grp == 0) ? j : 31 - j;
      if (ti > lim) continue;        // uniform scalar branch
      const int rb = (grp == 0) ? rb0 : rb1;
      const bf16x8 b0 = (grp == 0) ? aq0[0] : aq1[0];
      const bf16x8 b1 = (grp == 0) ? aq0[1] : aq1[1];

      float pv[4][4];
#pragma unroll
      for (int t4 = 0; t4 < 4; ++t4) {
        // S^T tile: A = K-frag (m=key=lane&15 -> row key0s+t4*16+c)
        const int krow = t4 * 16 + c;
        const bf16x8 k0f = *reinterpret_cast<const bf16x8*>(&Kc[krow * 64 + ((g) ^ (c & 7)) * 8]);
        const bf16x8 k1f = *reinterpret_cast<const bf16x8*>(&Kc[krow * 64 + ((4 + g) ^ (c & 7)) * 8]);
        floatx4 sa = zero4;
        sa = MFMA16(k0f, b0, sa);
        sa = MFMA16(k1f, b1, sa);
        // C/D: lane c = q-col, reg r -> key = key0s + t4*16 + g*4 + r
        if (ti == lim) {             // diagonal tile: causal mask
          const int q = rb + c;
#pragma unroll
          for (int r = 0; r < 4; ++r) {
            const int key = key0s + t4 * 16 + g * 4 + r;
            const float e = EXP2F(sa[r] * SCALE);
            pv[t4][r] = (key <= q) ? e : 0.f;
          }
        } else {
#pragma unroll
          for (int r = 0; r < 4; ++r) pv[t4][r] = EXP2F(sa[r] * SCALE);
        }
      }
      // l partial (each lane's 16 values all belong to q = rb+c)
      float lsum = 0.f;
#pragma unroll
      for (int t4 = 0; t4 < 4; ++t4)
        lsum += (pv[t4][0] + pv[t4][1]) + (pv[t4][2] + pv[t4][3]);
      if (grp == 0) l0 += lsum; else l1 += lsum;

      // PV: O^T += V^T * P^T via mfma 16x16x16 (P^T regs ARE the B-frag)
#pragma unroll
      for (int t4 = 0; t4 < 4; ++t4) {
        union { unsigned u[2]; shortx4 v; } pk;
        pk.u[0] = pack_bf2(pv[t4][0], pv[t4][1]);
        pk.u[1] = pack_bf2(pv[t4][2], pv[t4][3]);
        const int cc = t4 * 2 + (g >> 1);              // V key-chunk index (0..7)
        const int ko = (g & 1) * 4;                    // within-chunk key
#pragma unroll
        for (int td = 0; td < 4; ++td) {
          const shortx4 va = *reinterpret_cast<const shortx4*>(
              &Vc[(td * 16 + c) * 64 + (cc ^ (c & 7)) * 8 + ko]);
          if (grp == 0) oacc0[td] = MFMA16K16(va, pk.v, oacc0[td]);
          else          oacc1[td] = MFMA16K16(va, pk.v, oacc1[td]);
        }
      }
    }
    __builtin_amdgcn_s_barrier();   // all waves done reading buf[cur] before
                                    // next iter's stage overwrites it
  }

  // l: reduce across quads (q = c; partial per quad g) then normalize+store
#pragma unroll
  for (int grp = 0; grp < 2; ++grp) {
    float ls = (grp == 0) ? l0 : l1;
    ls += __shfl_xor(ls, 16, 64);
    ls += __shfl_xor(ls, 32, 64);
    const float inv = 1.f / ls;
    const int q = ((grp == 0) ? rb0 : rb1) + c;
    ushort_t* ob = &obuf[((size_t)(b * 2048 + q) * 16 + h) * 64];
#pragma unroll
    for (int td = 0; td < 4; ++td) {
      const floatx4 oa = (grp == 0) ? oacc0[td] : oacc1[td];
      ushortx4 pk;
#pragma unroll
      for (int r = 0; r < 4; ++r) pk[r] = f2bfu(oa[r] * inv);
      *reinterpret_cast<ushortx4*>(&ob[td * 16 + g * 4]) = pk;
    }
  }
}

// ---------------------------------------------------------------------------
// Output projection: out[m,n] = sum_k O[m,k] * Wp[n,k] + bp[n], fp32 out.
// R9 body. XCD remap as in gemm_qkv.
// ---------------------------------------------------------------------------
__global__ __launch_bounds__(256) void gemm_proj(
    const ushort_t* __restrict__ A, const ushort_t* __restrict__ Wp,
    const float* __restrict__ bias, float* __restrict__ out)
{
  const int L = (int)(blockIdx.x + 64 * blockIdx.y);  // grid (64,8), L in [0,512)
  const int rr = L & 7, mm = L >> 3;                  // mm 0..63
  const int m0 = (rr + 8 * (mm & 7)) * 128;
  const int n0 = (mm >> 3) * 128;

  __shared__ ushort_t Al[128 * 64];
  __shared__ ushort_t Bl[128 * 64];
  const int tid = threadIdx.x;
  const int w = tid >> 6, lane = tid & 63, g = lane >> 4, c = lane & 15;
  const int wm = w >> 1, wn = w & 1;
  const int cswz = c & 7;

  floatx4 acc[4][4];
  const floatx4 zero4 = {0.f, 0.f, 0.f, 0.f};
#pragma unroll
  for (int i = 0; i < 4; ++i)
#pragma unroll
    for (int j = 0; j < 4; ++j) acc[i][j] = zero4;

  const int srow = tid >> 3;
  const int gsw  = ((tid & 7) ^ (srow & 7)) * 8;

  for (int k0 = 0; k0 < 1024; k0 += 64) {
#pragma unroll
    for (int p = 0; p < 4; ++p) {
      const int row = p * 32 + srow;
      gl_lds16(&A [(size_t)(m0 + row) * 1024 + k0 + gsw], &Al[p * 2048 + tid * 8]);
      gl_lds16(&Wp[(size_t)(n0 + row) * 1024 + k0 + gsw], &Bl[p * 2048 + tid * 8]);
    }
    __syncthreads();
#pragma unroll
    for (int kk = 0; kk < 2; ++kk) {
      bf16x8 af[4], bfr[4];
#pragma unroll
      for (int i = 0; i < 4; ++i) {
        const int sw = ((kk * 4 + g) ^ cswz) * 8;
        af[i]  = *reinterpret_cast<const bf16x8*>(&Al[(wm * 64 + i * 16 + c) * 64 + sw]);
        bfr[i] = *reinterpret_cast<const bf16x8*>(&Bl[(wn * 64 + i * 16 + c) * 64 + sw]);
      }
#pragma unroll
      for (int i = 0; i < 4; ++i)
#pragma unroll
        for (int j = 0; j < 4; ++j)
          acc[i][j] = MFMA16(af[i], bfr[j], acc[i][j]);
    }
    __syncthreads();
  }

#pragma unroll
  for (int i = 0; i < 4; ++i) {
#pragma unroll
    for (int j = 0; j < 4; ++j) {
      const int n = n0 + wn * 64 + j * 16 + c;
      const float bv = bias[n];
#pragma unroll
      for (int r = 0; r < 4; ++r) {
        const int m = m0 + wm * 64 + i * 16 + g * 4 + r;
        out[(size_t)m * 1024 + n] = acc[i][j][r] + bv;
      }
    }
  }
}

extern "C" void kernel_launch(void* const* d_in, const int* in_sizes, int n_in,
                              void* d_out, int out_size, void* d_ws, size_t ws_size,
                              hipStream_t stream) {
  const float* x  = (const float*)d_in[0];
  const float* Wk = (const float*)d_in[1];   // input order: x, Wk, Wq, Wv, Wp, bp
  const float* Wq = (const float*)d_in[2];
  const float* Wv = (const float*)d_in[3];
  const float* Wp = (const float*)d_in[4];
  const float* bp = (const float*)d_in[5];
  float* out = (float*)d_out;

  char* ws = (char*)d_ws;
  const size_t SZ_X = (size_t)8192 * 1024 * 2;  // 16 MB bf16
  const size_t SZ_W = (size_t)1024 * 1024 * 2;  //  2 MB bf16
  ushort_t* xb    = (ushort_t*)ws;  ws += SZ_X;  // xb..wpb contiguous (cvt_all dst)
  ushort_t* wkb   = (ushort_t*)ws;  ws += SZ_W;
  ushort_t* wqb   = (ushort_t*)ws;  ws += SZ_W;
  ushort_t* wvb   = (ushort_t*)ws;  ws += SZ_W;
  ushort_t* wpb   = (ushort_t*)ws;  ws += SZ_W;
  ushort_t* qbuf  = (ushort_t*)ws;  ws += SZ_X;
  ushort_t* kbuf  = (ushort_t*)ws;  ws += SZ_X;
  ushort_t* vtbuf = (ushort_t*)ws;  ws += SZ_X;
  ushort_t* obuf  = xb;  // x is consumed by gemm_qkv before attn writes obuf

  cvt_all<<<12288, 256, 0, stream>>>(x, Wk, Wq, Wv, Wp, (ushortx4*)xb);

  gemm_qkv<<<dim3(64, 8, 3), 256, 0, stream>>>(xb, wqb, wkb, wvb, qbuf, kbuf, vtbuf);
  attn_kernel<<<dim3(16, 16, 4), 256, 0, stream>>>(qbuf, kbuf, vtbuf, obuf);
  gemm_proj<<<dim3(64, 8), 256, 0, stream>>>(obuf, wpb, bp, out);
}